// Round 1
// baseline (626.987 us; speedup 1.0000x reference)
//
#include <hip/hip_runtime.h>
#include <math.h>

#define Bn 16
#define Tn 128
#define Sn 128
#define Dn 512
#define Hn 100

__device__ __forceinline__ float softplus_f(float x) {
    // stable: max(x,0) + log(1+exp(-|x|))
    return fmaxf(x, 0.0f) + __logf(1.0f + __expf(-fabsf(x)));
}

// ---------------------------------------------------------------------------
// Generic tiled fp32 GEMM: C[m][n] = sum_k A[m][k] * B(n,k)
//   BLAYOUT 0: B is N x K row-major (NT)   -> B[n*ldb + k]
//   BLAYOUT 1: B is K x N row-major (NN)   -> B[k*ldb + n]  (requires N%64==0)
//   EPI 0: plain store C[m*ldc + n] (guard n<N)
//   EPI 1: tanh + transposed store: m = b*Tn + t, store C[t*(Bn*Dn) + b*Dn + n]
// 64x64 tile, BK=16, 256 threads, 4x4 per thread. M%64==0, K%16==0 required.
// ---------------------------------------------------------------------------
template<int BLAYOUT, int EPI>
__global__ __launch_bounds__(256)
void gemm_tile(const float* __restrict__ A, const float* __restrict__ Bm,
               float* __restrict__ C,
               int M, int N, int K, int lda, int ldb, int ldc,
               long sA, long sB, long sC)
{
    __shared__ float As[16][68];
    __shared__ float Bs[16][68];
    const int tid = threadIdx.x;
    const int tx = tid & 15, ty = tid >> 4;
    const int n0 = blockIdx.x * 64;
    const int m0 = blockIdx.y * 64;
    const int bz = blockIdx.z;
    A  += (long)bz * sA;
    Bm += (long)bz * sB;
    C  += (long)bz * sC;

    const int lm = tid >> 2;        // 0..63 (row within tile)
    const int lk = (tid & 3) * 4;   // 0,4,8,12 (k quad)
    const int nk = tid >> 4;        // 0..15 (k row for NN B)
    const int nn = (tid & 15) * 4;  // 0..60 (n quad for NN B)

    float acc[4][4] = {};

    for (int k0 = 0; k0 < K; k0 += 16) {
        float4 av = *(const float4*)&A[(long)(m0 + lm) * lda + k0 + lk];
        As[lk + 0][lm] = av.x; As[lk + 1][lm] = av.y;
        As[lk + 2][lm] = av.z; As[lk + 3][lm] = av.w;
        if (BLAYOUT == 0) {
            float4 bv = make_float4(0.f, 0.f, 0.f, 0.f);
            if (n0 + lm < N)
                bv = *(const float4*)&Bm[(long)(n0 + lm) * ldb + k0 + lk];
            Bs[lk + 0][lm] = bv.x; Bs[lk + 1][lm] = bv.y;
            Bs[lk + 2][lm] = bv.z; Bs[lk + 3][lm] = bv.w;
        } else {
            float4 bv = *(const float4*)&Bm[(long)(k0 + nk) * ldb + n0 + nn];
            *(float4*)&Bs[nk][nn] = bv;
        }
        __syncthreads();
        #pragma unroll
        for (int kk = 0; kk < 16; ++kk) {
            float4 a = *(const float4*)&As[kk][ty * 4];
            float4 b = *(const float4*)&Bs[kk][tx * 4];
            acc[0][0] = fmaf(a.x, b.x, acc[0][0]);
            acc[0][1] = fmaf(a.x, b.y, acc[0][1]);
            acc[0][2] = fmaf(a.x, b.z, acc[0][2]);
            acc[0][3] = fmaf(a.x, b.w, acc[0][3]);
            acc[1][0] = fmaf(a.y, b.x, acc[1][0]);
            acc[1][1] = fmaf(a.y, b.y, acc[1][1]);
            acc[1][2] = fmaf(a.y, b.z, acc[1][2]);
            acc[1][3] = fmaf(a.y, b.w, acc[1][3]);
            acc[2][0] = fmaf(a.z, b.x, acc[2][0]);
            acc[2][1] = fmaf(a.z, b.y, acc[2][1]);
            acc[2][2] = fmaf(a.z, b.z, acc[2][2]);
            acc[2][3] = fmaf(a.z, b.w, acc[2][3]);
            acc[3][0] = fmaf(a.w, b.x, acc[3][0]);
            acc[3][1] = fmaf(a.w, b.y, acc[3][1]);
            acc[3][2] = fmaf(a.w, b.z, acc[3][2]);
            acc[3][3] = fmaf(a.w, b.w, acc[3][3]);
        }
        __syncthreads();
    }

    if (EPI == 0) {
        #pragma unroll
        for (int i = 0; i < 4; ++i) {
            int m = m0 + ty * 4 + i;
            #pragma unroll
            for (int j = 0; j < 4; ++j) {
                int n = n0 + tx * 4 + j;
                if (n < N) C[(long)m * ldc + n] = acc[i][j];
            }
        }
    } else {
        #pragma unroll
        for (int i = 0; i < 4; ++i) {
            int m = m0 + ty * 4 + i;
            int bb = m >> 7, t = m & 127;   // m = b*Tn + t
            #pragma unroll
            for (int j = 0; j < 4; ++j) {
                int n = n0 + tx * 4 + j;
                C[(long)t * (Bn * Dn) + bb * Dn + n] = tanhf(acc[i][j]);
            }
        }
    }
}

// ---------------------------------------------------------------------------
// Softmax over S per (b,t) row; writes av directly in output (T,B,S) layout.
// ---------------------------------------------------------------------------
__global__ __launch_bounds__(128)
void softmax_k(const float* __restrict__ algn, float* __restrict__ av_out)
{
    const int bt = blockIdx.x;          // b*Tn + t
    const int b = bt >> 7, t = bt & 127;
    const int s = threadIdx.x;
    float v = algn[(long)bt * Sn + s];

    float m = v;
    #pragma unroll
    for (int o = 32; o > 0; o >>= 1) m = fmaxf(m, __shfl_xor(m, o));
    __shared__ float red[2];
    if ((s & 63) == 0) red[s >> 6] = m;
    __syncthreads();
    m = fmaxf(red[0], red[1]);

    float e = __expf(v - m);
    float sum = e;
    #pragma unroll
    for (int o = 32; o > 0; o >>= 1) sum += __shfl_xor(sum, o);
    __shared__ float red2[2];
    if ((s & 63) == 0) red2[s >> 6] = sum;
    __syncthreads();
    float inv = 1.0f / (red2[0] + red2[1]);

    av_out[(long)t * (Bn * Sn) + b * Sn + s] = e * inv;
}

// ---------------------------------------------------------------------------
// Copy input rows into second half of concat buffer (concat = [c | input]).
// ---------------------------------------------------------------------------
__global__ __launch_bounds__(128)
void copy_concat(const float* __restrict__ in, float* __restrict__ concat)
{
    const long m = blockIdx.x;
    const int tid = threadIdx.x;
    *(float4*)&concat[m * (2 * Dn) + Dn + tid * 4] =
        *(const float4*)&in[m * Dn + tid * 4];
}

// ---------------------------------------------------------------------------
// Fused h1 -> h2 -> h_mean/h_var. One block per (b,t). 128 threads (one per s).
// h1 tile in LDS with pitch Hn+1=101 (101 mod 32 = 5, coprime -> conflict-free).
// W2/b2/w_mean/w_var indices are loop-uniform -> scalar loads through K$.
// ---------------------------------------------------------------------------
__global__ __launch_bounds__(128)
void mlp_fused(const float* __restrict__ pt, const float* __restrict__ ps,
               const float* __restrict__ b1, const float* __restrict__ W2,
               const float* __restrict__ b2,
               const float* __restrict__ w_mean, const float* __restrict__ b_mean,
               const float* __restrict__ w_var, const float* __restrict__ b_var,
               float* __restrict__ mean_out, float* __restrict__ var_out)
{
    __shared__ float ptl[Hn];
    __shared__ float b1l[Hn];
    __shared__ float h1[Sn][Hn + 1];

    const int t = blockIdx.x, b = blockIdx.y;
    const int tid = threadIdx.x;            // = s

    if (tid < Hn) {
        ptl[tid] = pt[((long)b * Tn + t) * Hn + tid];
        b1l[tid] = b1[tid];
    }
    __syncthreads();

    const float* psrow = ps + ((long)b * Sn + tid) * Hn;
    float* h1row = &h1[tid][0];
    #pragma unroll
    for (int h = 0; h < Hn; h += 4) {
        float4 p = *(const float4*)&psrow[h];
        h1row[h + 0] = softplus_f(ptl[h + 0] + p.x + b1l[h + 0]);
        h1row[h + 1] = softplus_f(ptl[h + 1] + p.y + b1l[h + 1]);
        h1row[h + 2] = softplus_f(ptl[h + 2] + p.z + b1l[h + 2]);
        h1row[h + 3] = softplus_f(ptl[h + 3] + p.w + b1l[h + 3]);
    }
    // h1row written & read by the same thread only -> no barrier needed.

    float accM = 0.f, accV = 0.f;
    for (int g = 0; g < Hn; g += 4) {
        float a0 = b2[g + 0], a1 = b2[g + 1], a2 = b2[g + 2], a3 = b2[g + 3];
        const float* w0 = W2 + (long)(g + 0) * Hn;
        const float* w1 = W2 + (long)(g + 1) * Hn;
        const float* w2r = W2 + (long)(g + 2) * Hn;
        const float* w3 = W2 + (long)(g + 3) * Hn;
        #pragma unroll 4
        for (int h = 0; h < Hn; ++h) {
            float v = h1row[h];
            a0 = fmaf(v, w0[h], a0);
            a1 = fmaf(v, w1[h], a1);
            a2 = fmaf(v, w2r[h], a2);
            a3 = fmaf(v, w3[h], a3);
        }
        float h2;
        h2 = softplus_f(a0); accM = fmaf(h2, w_mean[g + 0], accM); accV = fmaf(h2, w_var[g + 0], accV);
        h2 = softplus_f(a1); accM = fmaf(h2, w_mean[g + 1], accM); accV = fmaf(h2, w_var[g + 1], accV);
        h2 = softplus_f(a2); accM = fmaf(h2, w_mean[g + 2], accM); accV = fmaf(h2, w_var[g + 2], accV);
        h2 = softplus_f(a3); accM = fmaf(h2, w_mean[g + 3], accM); accV = fmaf(h2, w_var[g + 3], accV);
    }

    const long o = ((long)b * Tn + t) * Sn + tid;
    mean_out[o] = softplus_f(accM + b_mean[0]);
    var_out[o]  = softplus_f(accV + b_var[0]);
}

// ---------------------------------------------------------------------------
extern "C" void kernel_launch(void* const* d_in, const int* in_sizes, int n_in,
                              void* d_out, int out_size, void* d_ws, size_t ws_size,
                              hipStream_t stream)
{
    (void)in_sizes; (void)n_in; (void)out_size; (void)ws_size;

    const float* input  = (const float*)d_in[0];
    const float* mem    = (const float*)d_in[1];
    const float* W_in   = (const float*)d_in[2];
    const float* W1     = (const float*)d_in[3];
    const float* b1     = (const float*)d_in[4];
    const float* W2     = (const float*)d_in[5];
    const float* b2     = (const float*)d_in[6];
    const float* w_mean = (const float*)d_in[7];
    const float* b_mean = (const float*)d_in[8];
    const float* w_var  = (const float*)d_in[9];
    const float* b_var  = (const float*)d_in[10];
    const float* W_out  = (const float*)d_in[11];

    float* out      = (float*)d_out;
    float* attn_out = out;                                  // (T,B,D)
    float* av_out   = out + (long)Tn * Bn * Dn;             // (T,B,S)
    float* mean_out = av_out + (long)Tn * Bn * Sn;          // (B,T,S)
    float* var_out  = mean_out + (long)Bn * Tn * Sn;        // (B,T,S)

    float* ws     = (float*)d_ws;
    float* ht     = ws;                                     // B*T*D
    float* pt     = ht + (long)Bn * Tn * Dn;                // B*T*H
    float* ps     = pt + (long)Bn * Tn * Hn;                // B*S*H
    float* algn   = ps + (long)Bn * Sn * Hn;                // B*T*S
    float* concat = algn + (long)Bn * Tn * Sn;              // B*T*2D

    // 1) ht = input @ W_in^T            (2048 x 512 x 512)
    gemm_tile<0, 0><<<dim3(Dn / 64, (Bn * Tn) / 64, 1), 256, 0, stream>>>(
        input, W_in, ht, Bn * Tn, Dn, Dn, Dn, Dn, Dn, 0L, 0L, 0L);

    // 2) pt = input @ W1[:, :D]^T       (2048 x 100 x 512)
    gemm_tile<0, 0><<<dim3(2, (Bn * Tn) / 64, 1), 256, 0, stream>>>(
        input, W1, pt, Bn * Tn, Hn, Dn, Dn, 2 * Dn, Hn, 0L, 0L, 0L);

    // 3) ps = mem @ W1[:, D:]^T         (2048 x 100 x 512)
    gemm_tile<0, 0><<<dim3(2, (Bn * Sn) / 64, 1), 256, 0, stream>>>(
        mem, W1 + Dn, ps, Bn * Sn, Hn, Dn, Dn, 2 * Dn, Hn, 0L, 0L, 0L);

    // 4) align = ht @ mem^T, batched over b   (128 x 128 x 512) x16
    gemm_tile<0, 0><<<dim3(Sn / 64, Tn / 64, Bn), 256, 0, stream>>>(
        ht, mem, algn, Tn, Sn, Dn, Dn, Dn, Sn,
        (long)Tn * Dn, (long)Sn * Dn, (long)Tn * Sn);

    // 5) softmax -> av directly into output slot (T,B,S)
    softmax_k<<<dim3(Bn * Tn), 128, 0, stream>>>(algn, av_out);

    // 6) c = av @ mem -> concat[:, :D], batched over b   (128 x 512 x 128) x16
    //    A reads av from the output slot in (T,B,S) layout: lda = Bn*Sn, batch stride = Sn
    gemm_tile<1, 0><<<dim3(Dn / 64, Tn / 64, Bn), 256, 0, stream>>>(
        av_out, mem, concat, Tn, Dn, Sn, Bn * Sn, Dn, 2 * Dn,
        (long)Sn, (long)Sn * Dn, (long)Tn * 2 * Dn);

    // 7) concat[:, D:] = input
    copy_concat<<<dim3(Bn * Tn), 128, 0, stream>>>(input, concat);

    // 8) attn_h = tanh(concat @ W_out^T), store transposed (T,B,D)
    gemm_tile<0, 1><<<dim3(Dn / 64, (Bn * Tn) / 64, 1), 256, 0, stream>>>(
        concat, W_out, attn_out, Bn * Tn, Dn, 2 * Dn, 2 * Dn, 2 * Dn, Dn, 0L, 0L, 0L);

    // 9) fused h1 -> h2 -> h_mean / h_var
    mlp_fused<<<dim3(Tn, Bn), 128, 0, stream>>>(
        pt, ps, b1, W2, b2, w_mean, b_mean, w_var, b_var, mean_out, var_out);
}

// Round 2
// 353.410 us; speedup vs baseline: 1.7741x; 1.7741x over previous
//
#include <hip/hip_runtime.h>
#include <math.h>

#define Bn 16
#define Tn 128
#define Sn 128
#define Dn 512
#define Hn 100

#define NP 112      // Hn padded to 16 (N of h2 GEMM)
#define KP 128      // Hn padded to 32 (K of h2 GEMM)
#define H1P 136     // LDS pitch for h1 rows, in bf16 elems (272 B: 2-way-free)

typedef short short8 __attribute__((ext_vector_type(8)));
typedef float f32x4 __attribute__((ext_vector_type(4)));
typedef unsigned short ushort4v __attribute__((ext_vector_type(4)));

__device__ __forceinline__ float softplus_f(float x) {
    return fmaxf(x, 0.0f) + __logf(1.0f + __expf(-fabsf(x)));
}

__device__ __forceinline__ unsigned short f2bf(float f) {
    unsigned u = __float_as_uint(f);
    unsigned r = u + 0x7FFFu + ((u >> 16) & 1u);   // RNE (finite inputs only)
    return (unsigned short)(r >> 16);
}

// ---------------------------------------------------------------------------
// Generic tiled fp32 GEMM: C[m][n] = sum_k A[m][k] * B(n,k)
//   BLAYOUT 0: B is N x K row-major (NT)   -> B[n*ldb + k]
//   BLAYOUT 1: B is K x N row-major (NN)   -> B[k*ldb + n]  (requires N%64==0)
//   EPI 0: plain store; EPI 1: tanh + transposed (T,B,D) store
// ---------------------------------------------------------------------------
template<int BLAYOUT, int EPI>
__global__ __launch_bounds__(256)
void gemm_tile(const float* __restrict__ A, const float* __restrict__ Bm,
               float* __restrict__ C,
               int M, int N, int K, int lda, int ldb, int ldc,
               long sA, long sB, long sC)
{
    __shared__ float As[16][68];
    __shared__ float Bs[16][68];
    const int tid = threadIdx.x;
    const int tx = tid & 15, ty = tid >> 4;
    const int n0 = blockIdx.x * 64;
    const int m0 = blockIdx.y * 64;
    const int bz = blockIdx.z;
    A  += (long)bz * sA;
    Bm += (long)bz * sB;
    C  += (long)bz * sC;

    const int lm = tid >> 2;
    const int lk = (tid & 3) * 4;
    const int nk = tid >> 4;
    const int nn = (tid & 15) * 4;

    float acc[4][4] = {};

    for (int k0 = 0; k0 < K; k0 += 16) {
        float4 av = *(const float4*)&A[(long)(m0 + lm) * lda + k0 + lk];
        As[lk + 0][lm] = av.x; As[lk + 1][lm] = av.y;
        As[lk + 2][lm] = av.z; As[lk + 3][lm] = av.w;
        if (BLAYOUT == 0) {
            float4 bv = make_float4(0.f, 0.f, 0.f, 0.f);
            if (n0 + lm < N)
                bv = *(const float4*)&Bm[(long)(n0 + lm) * ldb + k0 + lk];
            Bs[lk + 0][lm] = bv.x; Bs[lk + 1][lm] = bv.y;
            Bs[lk + 2][lm] = bv.z; Bs[lk + 3][lm] = bv.w;
        } else {
            float4 bv = *(const float4*)&Bm[(long)(k0 + nk) * ldb + n0 + nn];
            *(float4*)&Bs[nk][nn] = bv;
        }
        __syncthreads();
        #pragma unroll
        for (int kk = 0; kk < 16; ++kk) {
            float4 a = *(const float4*)&As[kk][ty * 4];
            float4 b = *(const float4*)&Bs[kk][tx * 4];
            acc[0][0] = fmaf(a.x, b.x, acc[0][0]);
            acc[0][1] = fmaf(a.x, b.y, acc[0][1]);
            acc[0][2] = fmaf(a.x, b.z, acc[0][2]);
            acc[0][3] = fmaf(a.x, b.w, acc[0][3]);
            acc[1][0] = fmaf(a.y, b.x, acc[1][0]);
            acc[1][1] = fmaf(a.y, b.y, acc[1][1]);
            acc[1][2] = fmaf(a.y, b.z, acc[1][2]);
            acc[1][3] = fmaf(a.y, b.w, acc[1][3]);
            acc[2][0] = fmaf(a.z, b.x, acc[2][0]);
            acc[2][1] = fmaf(a.z, b.y, acc[2][1]);
            acc[2][2] = fmaf(a.z, b.z, acc[2][2]);
            acc[2][3] = fmaf(a.z, b.w, acc[2][3]);
            acc[3][0] = fmaf(a.w, b.x, acc[3][0]);
            acc[3][1] = fmaf(a.w, b.y, acc[3][1]);
            acc[3][2] = fmaf(a.w, b.z, acc[3][2]);
            acc[3][3] = fmaf(a.w, b.w, acc[3][3]);
        }
        __syncthreads();
    }

    if (EPI == 0) {
        #pragma unroll
        for (int i = 0; i < 4; ++i) {
            int m = m0 + ty * 4 + i;
            #pragma unroll
            for (int j = 0; j < 4; ++j) {
                int n = n0 + tx * 4 + j;
                if (n < N) C[(long)m * ldc + n] = acc[i][j];
            }
        }
    } else {
        #pragma unroll
        for (int i = 0; i < 4; ++i) {
            int m = m0 + ty * 4 + i;
            int bb = m >> 7, t = m & 127;
            #pragma unroll
            for (int j = 0; j < 4; ++j) {
                int n = n0 + tx * 4 + j;
                C[(long)t * (Bn * Dn) + bb * Dn + n] = tanhf(acc[i][j]);
            }
        }
    }
}

// ---------------------------------------------------------------------------
__global__ __launch_bounds__(128)
void softmax_k(const float* __restrict__ algn, float* __restrict__ av_out)
{
    const int bt = blockIdx.x;
    const int b = bt >> 7, t = bt & 127;
    const int s = threadIdx.x;
    float v = algn[(long)bt * Sn + s];

    float m = v;
    #pragma unroll
    for (int o = 32; o > 0; o >>= 1) m = fmaxf(m, __shfl_xor(m, o));
    __shared__ float red[2];
    if ((s & 63) == 0) red[s >> 6] = m;
    __syncthreads();
    m = fmaxf(red[0], red[1]);

    float e = __expf(v - m);
    float sum = e;
    #pragma unroll
    for (int o = 32; o > 0; o >>= 1) sum += __shfl_xor(sum, o);
    __shared__ float red2[2];
    if ((s & 63) == 0) red2[s >> 6] = sum;
    __syncthreads();
    float inv = 1.0f / (red2[0] + red2[1]);

    av_out[(long)t * (Bn * Sn) + b * Sn + s] = e * inv;
}

// ---------------------------------------------------------------------------
__global__ __launch_bounds__(128)
void copy_concat(const float* __restrict__ in, float* __restrict__ concat)
{
    const long m = blockIdx.x;
    const int tid = threadIdx.x;
    *(float4*)&concat[m * (2 * Dn) + Dn + tid * 4] =
        *(const float4*)&in[m * Dn + tid * 4];
}

// ---------------------------------------------------------------------------
// W2 (Hn x Hn fp32) -> zero-padded bf16 [NP][KP] in workspace.
// ---------------------------------------------------------------------------
__global__ __launch_bounds__(128)
void w2_to_bf16(const float* __restrict__ W2, unsigned short* __restrict__ w2b)
{
    const int n = blockIdx.x;        // 0..NP-1
    const int k = threadIdx.x;       // 0..KP-1
    float v = (n < Hn && k < Hn) ? W2[n * Hn + k] : 0.0f;
    w2b[n * KP + k] = f2bf(v);
}

// ---------------------------------------------------------------------------
// Fused MLP via MFMA. One block per (b,t); 256 threads = 4 waves.
// h1 = softplus(pt + ps + b1) staged to LDS as bf16 [Sn][H1P] (K zero-padded).
// h2 = h1 @ W2^T via mfma_f32_16x16x32_bf16; epilogue reduces over g with
// w_mean/w_var, butterfly over the 16 C-columns, softplus, store (B,T,S).
// ---------------------------------------------------------------------------
__global__ __launch_bounds__(256)
void mlp_mfma(const float* __restrict__ pt, const float* __restrict__ ps,
              const float* __restrict__ b1,
              const unsigned short* __restrict__ w2b,
              const float* __restrict__ b2,
              const float* __restrict__ w_mean, const float* __restrict__ b_mean,
              const float* __restrict__ w_var, const float* __restrict__ b_var,
              float* __restrict__ mean_out, float* __restrict__ var_out)
{
    __shared__ unsigned short h1s[Sn * H1P];     // 34816 B
    __shared__ float ptl[Hn];
    __shared__ float b1l[Hn];

    const int t = blockIdx.x, b = blockIdx.y;
    const int tid = threadIdx.x;

    if (tid < Hn) {
        ptl[tid] = pt[((long)b * Tn + t) * Hn + tid];
        b1l[tid] = b1[tid];
    }
    __syncthreads();

    // ---- stage h1 (each thread: half a row) ----
    {
        const int s = tid >> 1;
        const int half = tid & 1;
        const int h0 = half ? 52 : 0;
        const int h1e = half ? 100 : 52;
        const float* psrow = ps + ((long)b * Sn + s) * Hn;
        unsigned short* row = &h1s[s * H1P];
        for (int h = h0; h < h1e; h += 4) {
            float4 p = *(const float4*)&psrow[h];
            ushort4v q;
            q.x = f2bf(softplus_f(ptl[h + 0] + p.x + b1l[h + 0]));
            q.y = f2bf(softplus_f(ptl[h + 1] + p.y + b1l[h + 1]));
            q.z = f2bf(softplus_f(ptl[h + 2] + p.z + b1l[h + 2]));
            q.w = f2bf(softplus_f(ptl[h + 3] + p.w + b1l[h + 3]));
            *(ushort4v*)&row[h] = q;
        }
        if (half) {  // zero K-pad 100..127
            ushort4v z = {0, 0, 0, 0};
            #pragma unroll
            for (int h = 100; h < KP; h += 4) *(ushort4v*)&row[h] = z;
        }
    }
    __syncthreads();

    // ---- MFMA: 128x112x128, wave w owns rows w*32 .. w*32+31 ----
    const int wave = tid >> 6;
    const int lane = tid & 63;
    const int lm = lane & 15;          // m / n within tile
    const int lq = lane >> 4;          // k quad
    const int m0w = wave * 32;

    f32x4 acc[2][7];
    #pragma unroll
    for (int i = 0; i < 2; ++i)
        #pragma unroll
        for (int j = 0; j < 7; ++j)
            acc[i][j] = (f32x4){0.f, 0.f, 0.f, 0.f};

    #pragma unroll
    for (int ks = 0; ks < 4; ++ks) {
        const int k0 = ks * 32 + lq * 8;
        short8 a0 = *(const short8*)&h1s[(m0w + lm) * H1P + k0];
        short8 a1 = *(const short8*)&h1s[(m0w + 16 + lm) * H1P + k0];
        short8 bf[7];
        #pragma unroll
        for (int nt = 0; nt < 7; ++nt)
            bf[nt] = *(const short8*)&w2b[(nt * 16 + lm) * KP + k0];
        #pragma unroll
        for (int nt = 0; nt < 7; ++nt) {
            acc[0][nt] = __builtin_amdgcn_mfma_f32_16x16x32_bf16(a0, bf[nt], acc[0][nt], 0, 0, 0);
            acc[1][nt] = __builtin_amdgcn_mfma_f32_16x16x32_bf16(a1, bf[nt], acc[1][nt], 0, 0, 0);
        }
    }

    // ---- epilogue: h2 = softplus(acc + b2); dot with w_mean / w_var ----
    float sM[2][4] = {}, sV[2][4] = {};
    #pragma unroll
    for (int nt = 0; nt < 7; ++nt) {
        int g = nt * 16 + lm;
        if (g < Hn) {
            float bg = b2[g], wm = w_mean[g], wv = w_var[g];
            #pragma unroll
            for (int mt = 0; mt < 2; ++mt) {
                #pragma unroll
                for (int r = 0; r < 4; ++r) {
                    float h2 = softplus_f(acc[mt][nt][r] + bg);
                    sM[mt][r] = fmaf(h2, wm, sM[mt][r]);
                    sV[mt][r] = fmaf(h2, wv, sV[mt][r]);
                }
            }
        }
    }
    #pragma unroll
    for (int off = 1; off < 16; off <<= 1) {
        #pragma unroll
        for (int mt = 0; mt < 2; ++mt)
            #pragma unroll
            for (int r = 0; r < 4; ++r) {
                sM[mt][r] += __shfl_xor(sM[mt][r], off);
                sV[mt][r] += __shfl_xor(sV[mt][r], off);
            }
    }

    if (lm == 0) {
        const float bm = b_mean[0], bv = b_var[0];
        const long base = ((long)b * Tn + t) * Sn;
        #pragma unroll
        for (int mt = 0; mt < 2; ++mt) {
            #pragma unroll
            for (int r = 0; r < 4; ++r) {
                int row = m0w + mt * 16 + lq * 4 + r;
                mean_out[base + row] = softplus_f(sM[mt][r] + bm);
                var_out[base + row]  = softplus_f(sV[mt][r] + bv);
            }
        }
    }
}

// ---------------------------------------------------------------------------
extern "C" void kernel_launch(void* const* d_in, const int* in_sizes, int n_in,
                              void* d_out, int out_size, void* d_ws, size_t ws_size,
                              hipStream_t stream)
{
    (void)in_sizes; (void)n_in; (void)out_size; (void)ws_size;

    const float* input  = (const float*)d_in[0];
    const float* mem    = (const float*)d_in[1];
    const float* W_in   = (const float*)d_in[2];
    const float* W1     = (const float*)d_in[3];
    const float* b1     = (const float*)d_in[4];
    const float* W2     = (const float*)d_in[5];
    const float* b2     = (const float*)d_in[6];
    const float* w_mean = (const float*)d_in[7];
    const float* b_mean = (const float*)d_in[8];
    const float* w_var  = (const float*)d_in[9];
    const float* b_var  = (const float*)d_in[10];
    const float* W_out  = (const float*)d_in[11];

    float* out      = (float*)d_out;
    float* attn_out = out;                                  // (T,B,D)
    float* av_out   = out + (long)Tn * Bn * Dn;             // (T,B,S)
    float* mean_out = av_out + (long)Tn * Bn * Sn;          // (B,T,S)
    float* var_out  = mean_out + (long)Bn * Tn * Sn;        // (B,T,S)

    float* ws     = (float*)d_ws;
    float* ht     = ws;                                     // B*T*D
    float* pt     = ht + (long)Bn * Tn * Dn;                // B*T*H
    float* ps     = pt + (long)Bn * Tn * Hn;                // B*S*H
    float* algn   = ps + (long)Bn * Sn * Hn;                // B*T*S
    float* concat = algn + (long)Bn * Tn * Sn;              // B*T*2D
    unsigned short* w2b = (unsigned short*)(concat + (long)Bn * Tn * 2 * Dn);  // NP*KP bf16

    // 0) W2 -> bf16 padded
    w2_to_bf16<<<dim3(NP), KP, 0, stream>>>(W2, w2b);

    // 1) ht = input @ W_in^T            (2048 x 512 x 512)
    gemm_tile<0, 0><<<dim3(Dn / 64, (Bn * Tn) / 64, 1), 256, 0, stream>>>(
        input, W_in, ht, Bn * Tn, Dn, Dn, Dn, Dn, Dn, 0L, 0L, 0L);

    // 2) pt = input @ W1[:, :D]^T       (2048 x 100 x 512)
    gemm_tile<0, 0><<<dim3(2, (Bn * Tn) / 64, 1), 256, 0, stream>>>(
        input, W1, pt, Bn * Tn, Hn, Dn, Dn, 2 * Dn, Hn, 0L, 0L, 0L);

    // 3) ps = mem @ W1[:, D:]^T         (2048 x 100 x 512)
    gemm_tile<0, 0><<<dim3(2, (Bn * Sn) / 64, 1), 256, 0, stream>>>(
        mem, W1 + Dn, ps, Bn * Sn, Hn, Dn, Dn, 2 * Dn, Hn, 0L, 0L, 0L);

    // 4) align = ht @ mem^T, batched over b
    gemm_tile<0, 0><<<dim3(Sn / 64, Tn / 64, Bn), 256, 0, stream>>>(
        ht, mem, algn, Tn, Sn, Dn, Dn, Dn, Sn,
        (long)Tn * Dn, (long)Sn * Dn, (long)Tn * Sn);

    // 5) softmax -> av directly into output slot (T,B,S)
    softmax_k<<<dim3(Bn * Tn), 128, 0, stream>>>(algn, av_out);

    // 6) c = av @ mem -> concat[:, :D], batched over b
    gemm_tile<1, 0><<<dim3(Dn / 64, Tn / 64, Bn), 256, 0, stream>>>(
        av_out, mem, concat, Tn, Dn, Sn, Bn * Sn, Dn, 2 * Dn,
        (long)Sn, (long)Sn * Dn, (long)Tn * 2 * Dn);

    // 7) concat[:, D:] = input
    copy_concat<<<dim3(Bn * Tn), 128, 0, stream>>>(input, concat);

    // 8) attn_h = tanh(concat @ W_out^T), store transposed (T,B,D)
    gemm_tile<0, 1><<<dim3(Dn / 64, (Bn * Tn) / 64, 1), 256, 0, stream>>>(
        concat, W_out, attn_out, Bn * Tn, Dn, 2 * Dn, 2 * Dn, 2 * Dn, Dn, 0L, 0L, 0L);

    // 9) fused MLP via MFMA
    mlp_mfma<<<dim3(Tn, Bn), 256, 0, stream>>>(
        pt, ps, b1, w2b, b2, w_mean, b_mean, w_var, b_var, mean_out, var_out);
}

// Round 4
// 247.529 us; speedup vs baseline: 2.5330x; 1.4277x over previous
//
#include <hip/hip_runtime.h>
#include <math.h>

#define Bn 16
#define Tn 128
#define Sn 128
#define Dn 512
#define Hn 100

typedef short short8 __attribute__((ext_vector_type(8)));
typedef float f32x4 __attribute__((ext_vector_type(4)));
typedef unsigned short ushort4v __attribute__((ext_vector_type(4)));

__device__ __forceinline__ float softplus_f(float x) {
    return fmaxf(x, 0.0f) + __logf(1.0f + __expf(-fabsf(x)));
}
__device__ __forceinline__ unsigned short f2bf(float f) {
    unsigned u = __float_as_uint(f);
    unsigned r = u + 0x7FFFu + ((u >> 16) & 1u);
    return (unsigned short)(r >> 16);
}
__device__ __forceinline__ float bf2f(unsigned short h) {
    return __uint_as_float(((unsigned)h) << 16);
}
struct BfPair { unsigned short h, l; };
__device__ __forceinline__ BfPair split2(float x) {
    BfPair p;
    p.h = f2bf(x);
    p.l = f2bf(x - bf2f(p.h));
    return p;
}

// ---------------------------------------------------------------------------
// Fused conversion: input/mem/W_in -> hi+lo bf16; W1/W_out -> hi bf16;
// W2 -> padded [112][128] bf16; input hi also into concatb right half.
// 1024 elems per block, 4 per thread.
// ---------------------------------------------------------------------------
__global__ __launch_bounds__(256)
void conv_all(const float* __restrict__ input, const float* __restrict__ mem,
              const float* __restrict__ W_in, const float* __restrict__ W1,
              const float* __restrict__ W_out, const float* __restrict__ W2,
              unsigned short* __restrict__ inh, unsigned short* __restrict__ inl,
              unsigned short* __restrict__ memh, unsigned short* __restrict__ meml,
              unsigned short* __restrict__ winh, unsigned short* __restrict__ winl,
              unsigned short* __restrict__ w1b, unsigned short* __restrict__ woutb,
              unsigned short* __restrict__ w2b, unsigned short* __restrict__ concatb)
{
    long gid = (long)blockIdx.x * 1024 + (long)threadIdx.x * 4;
    if (gid < 1048576) {
        float4 v = *(const float4*)&input[gid];
        BfPair a = split2(v.x), b = split2(v.y), c = split2(v.z), d = split2(v.w);
        ushort4v h = {a.h, b.h, c.h, d.h};
        ushort4v l = {a.l, b.l, c.l, d.l};
        *(ushort4v*)&inh[gid] = h;
        *(ushort4v*)&inl[gid] = l;
        long row = gid >> 9; int col = (int)(gid & 511);
        *(ushort4v*)&concatb[row * 1024 + 512 + col] = h;
    } else if (gid < 2097152) {
        long e = gid - 1048576;
        float4 v = *(const float4*)&mem[e];
        BfPair a = split2(v.x), b = split2(v.y), c = split2(v.z), d = split2(v.w);
        ushort4v h = {a.h, b.h, c.h, d.h};
        ushort4v l = {a.l, b.l, c.l, d.l};
        *(ushort4v*)&memh[e] = h;
        *(ushort4v*)&meml[e] = l;
    } else if (gid < 2359296) {
        long e = gid - 2097152;
        float4 v = *(const float4*)&W_in[e];
        BfPair a = split2(v.x), b = split2(v.y), c = split2(v.z), d = split2(v.w);
        ushort4v h = {a.h, b.h, c.h, d.h};
        ushort4v l = {a.l, b.l, c.l, d.l};
        *(ushort4v*)&winh[e] = h;
        *(ushort4v*)&winl[e] = l;
    } else if (gid < 2461696) {
        long e = gid - 2359296;
        float4 v = *(const float4*)&W1[e];
        ushort4v h = {f2bf(v.x), f2bf(v.y), f2bf(v.z), f2bf(v.w)};
        *(ushort4v*)&w1b[e] = h;
    } else if (gid < 2985984) {
        long e = gid - 2461696;
        float4 v = *(const float4*)&W_out[e];
        ushort4v h = {f2bf(v.x), f2bf(v.y), f2bf(v.z), f2bf(v.w)};
        *(ushort4v*)&woutb[e] = h;
    } else {
        long e = gid - 2985984;           // 0 .. 14335 over [112][128]
        int n = (int)(e >> 7), k = (int)(e & 127);
        ushort4v h;
        #pragma unroll
        for (int j = 0; j < 4; ++j) {
            int kj = k + j;
            float val = (n < Hn && kj < Hn) ? W2[n * Hn + kj] : 0.0f;
            h[j] = f2bf(val);
        }
        *(ushort4v*)&w2b[n * 128 + k] = h;
    }
}

// ---------------------------------------------------------------------------
// memT_b[b][d][s] (bf16) from mem[b][s][d] (fp32) via LDS tile.
// grid (Dn/64, Sn/64, Bn), 256 threads.
// ---------------------------------------------------------------------------
__global__ __launch_bounds__(256)
void transpose_mem(const float* __restrict__ mem, unsigned short* __restrict__ memTb)
{
    __shared__ float tile[64][65];
    const int d0 = blockIdx.x * 64, s0 = blockIdx.y * 64, b = blockIdx.z;
    const int tid = threadIdx.x;
    const int r = tid >> 2, cb = (tid & 3) * 16;

    const float* src = mem + ((long)b * Sn + s0 + r) * Dn + d0 + cb;
    #pragma unroll
    for (int j = 0; j < 4; ++j) {
        float4 v = *(const float4*)&src[j * 4];
        tile[r][cb + j * 4 + 0] = v.x;
        tile[r][cb + j * 4 + 1] = v.y;
        tile[r][cb + j * 4 + 2] = v.z;
        tile[r][cb + j * 4 + 3] = v.w;
    }
    __syncthreads();
    unsigned short* dst = memTb + ((long)b * Dn + d0 + r) * Sn + s0 + cb;
    #pragma unroll
    for (int j = 0; j < 4; ++j) {
        ushort4v q;
        q.x = f2bf(tile[cb + j * 4 + 0][r]);
        q.y = f2bf(tile[cb + j * 4 + 1][r]);
        q.z = f2bf(tile[cb + j * 4 + 2][r]);
        q.w = f2bf(tile[cb + j * 4 + 3][r]);
        *(ushort4v*)&dst[j * 4] = q;
    }
}

// ---------------------------------------------------------------------------
// bf16 MFMA GEMM, NT: C[m][n] = sum_k A[m][k]*B[n][k].
// Block tile 128(M) x 64(N), BK=64, 256 thr = 4 waves (2x2), wave tile 64x32.
// XOR-swizzled LDS (chunk p = c ^ (row&7)) -> conflict-free b128.
// SPLIT: A/B given as hi+lo bf16 pairs; 3 MFMAs (drops lo*lo).
// EPI 0: fp32 C (guard n<N)   1: bf16 hi/lo out (Cb, Cb2)
//     2: tanh + (t,b,d) fp32  3: bf16 out (Cb)
// Requires M%128==0, K%64==0, lda/ldb % 8 == 0.
// ---------------------------------------------------------------------------
template<int SPLIT, int EPI>
__global__ __launch_bounds__(256)
void mfma_gemm(const unsigned short* __restrict__ Ah, const unsigned short* __restrict__ Al,
               const unsigned short* __restrict__ Bh, const unsigned short* __restrict__ Bl,
               float* __restrict__ C, unsigned short* __restrict__ Cb,
               unsigned short* __restrict__ Cb2,
               int N, int K, int lda, int ldb, int ldc,
               long sA, long sB, long sC)
{
    __shared__ unsigned short As_[(SPLIT ? 2 : 1) * 128 * 64];
    __shared__ unsigned short Bs_[(SPLIT ? 2 : 1) * 64 * 64];
    unsigned short* Asl = As_ + 128 * 64;
    unsigned short* Bsl = Bs_ + 64 * 64;

    const int tid = threadIdx.x;
    const int n0 = blockIdx.x * 64;
    const long m0 = (long)blockIdx.y * 128;
    const int bz = blockIdx.z;
    Ah += (long)bz * sA;
    Bh += (long)bz * sB;
    if (SPLIT) { Al += (long)bz * sA; Bl += (long)bz * sB; }

    const int wid = tid >> 6, lane = tid & 63;
    const int lm = lane & 15, lq = lane >> 4;
    const int wm = wid & 1, wn = wid >> 1;

    const int ar = tid >> 1;             // A row 0..127
    const int ac = (tid & 1) * 4;        // A chunk base
    const int br = tid >> 2;             // B row 0..63
    const int bc = (tid & 3) * 2;        // B chunk base
    const bool bok = (n0 + br) < N;

    f32x4 acc[4][2];
    #pragma unroll
    for (int i = 0; i < 4; ++i)
        #pragma unroll
        for (int j = 0; j < 2; ++j)
            acc[i][j] = (f32x4){0.f, 0.f, 0.f, 0.f};

    for (int k0 = 0; k0 < K; k0 += 64) {
        __syncthreads();
        #pragma unroll
        for (int i = 0; i < 4; ++i) {
            int c = ac + i;
            int p = c ^ (ar & 7);
            *(short8*)&As_[ar * 64 + p * 8] =
                *(const short8*)&Ah[(m0 + ar) * lda + k0 + c * 8];
            if (SPLIT)
                *(short8*)&Asl[ar * 64 + p * 8] =
                    *(const short8*)&Al[(m0 + ar) * lda + k0 + c * 8];
        }
        #pragma unroll
        for (int i = 0; i < 2; ++i) {
            int c = bc + i;
            int p = c ^ (br & 7);
            short8 v = {0, 0, 0, 0, 0, 0, 0, 0};
            short8 vl = {0, 0, 0, 0, 0, 0, 0, 0};
            if (bok) {
                v = *(const short8*)&Bh[(long)(n0 + br) * ldb + k0 + c * 8];
                if (SPLIT) vl = *(const short8*)&Bl[(long)(n0 + br) * ldb + k0 + c * 8];
            }
            *(short8*)&Bs_[br * 64 + p * 8] = v;
            if (SPLIT) *(short8*)&Bsl[br * 64 + p * 8] = vl;
        }
        __syncthreads();
        #pragma unroll
        for (int kk = 0; kk < 2; ++kk) {
            short8 a[4], b[2], al_[4], bl_[2];
            #pragma unroll
            for (int mt = 0; mt < 4; ++mt) {
                int row = wm * 64 + mt * 16 + lm;
                int p = (kk * 4 + lq) ^ (lm & 7);
                a[mt] = *(const short8*)&As_[row * 64 + p * 8];
                if (SPLIT) al_[mt] = *(const short8*)&Asl[row * 64 + p * 8];
            }
            #pragma unroll
            for (int nt = 0; nt < 2; ++nt) {
                int row = wn * 32 + nt * 16 + lm;
                int p = (kk * 4 + lq) ^ (lm & 7);
                b[nt] = *(const short8*)&Bs_[row * 64 + p * 8];
                if (SPLIT) bl_[nt] = *(const short8*)&Bsl[row * 64 + p * 8];
            }
            #pragma unroll
            for (int mt = 0; mt < 4; ++mt)
                #pragma unroll
                for (int nt = 0; nt < 2; ++nt) {
                    if (SPLIT) {
                        acc[mt][nt] = __builtin_amdgcn_mfma_f32_16x16x32_bf16(
                            al_[mt], b[nt], acc[mt][nt], 0, 0, 0);
                        acc[mt][nt] = __builtin_amdgcn_mfma_f32_16x16x32_bf16(
                            a[mt], bl_[nt], acc[mt][nt], 0, 0, 0);
                    }
                    acc[mt][nt] = __builtin_amdgcn_mfma_f32_16x16x32_bf16(
                        a[mt], b[nt], acc[mt][nt], 0, 0, 0);
                }
        }
    }

    #pragma unroll
    for (int mt = 0; mt < 4; ++mt)
        #pragma unroll
        for (int nt = 0; nt < 2; ++nt)
            #pragma unroll
            for (int r = 0; r < 4; ++r) {
                long m = m0 + wm * 64 + mt * 16 + lq * 4 + r;
                int n = n0 + wn * 32 + nt * 16 + lm;
                float v = acc[mt][nt][r];
                if (EPI == 0) {
                    if (n < N) C[(long)bz * sC + m * ldc + n] = v;
                } else if (EPI == 1) {
                    unsigned short h = f2bf(v);
                    Cb[m * ldc + n] = h;
                    Cb2[m * ldc + n] = f2bf(v - bf2f(h));
                } else if (EPI == 2) {
                    long bb = m >> 7, tt = m & 127;
                    C[tt * (Bn * Dn) + bb * Dn + n] = tanhf(v);
                } else {
                    Cb[(long)bz * sC + m * ldc + n] = f2bf(v);
                }
            }
}

// ---------------------------------------------------------------------------
__global__ __launch_bounds__(128)
void softmax_k(const float* __restrict__ algn, float* __restrict__ av_out,
               unsigned short* __restrict__ avb)
{
    const int bt = blockIdx.x;
    const int b = bt >> 7, t = bt & 127;
    const int s = threadIdx.x;
    float v = algn[(long)bt * Sn + s];

    float m = v;
    #pragma unroll
    for (int o = 32; o > 0; o >>= 1) m = fmaxf(m, __shfl_xor(m, o));
    __shared__ float red[2];
    if ((s & 63) == 0) red[s >> 6] = m;
    __syncthreads();
    m = fmaxf(red[0], red[1]);

    float e = __expf(v - m);
    float sum = e;
    #pragma unroll
    for (int o = 32; o > 0; o >>= 1) sum += __shfl_xor(sum, o);
    __shared__ float red2[2];
    if ((s & 63) == 0) red2[s >> 6] = sum;
    __syncthreads();
    float inv = 1.0f / (red2[0] + red2[1]);

    float av = e * inv;
    av_out[(long)t * (Bn * Sn) + b * Sn + s] = av;
    avb[(long)bt * Sn + s] = f2bf(av);
}

// ---------------------------------------------------------------------------
// Fused MLP. Block = (t, b*2+half); 64 s-rows; 256 thr = 4 waves.
// h1 bf16 in LDS [64][128] XOR-swizzled; h2 via MFMA vs w2b (global, L1-hot).
// ---------------------------------------------------------------------------
__global__ __launch_bounds__(256)
void mlp_mfma2(const float* __restrict__ pt, const float* __restrict__ ps,
               const float* __restrict__ b1,
               const unsigned short* __restrict__ w2b,
               const float* __restrict__ b2,
               const float* __restrict__ w_mean, const float* __restrict__ b_mean,
               const float* __restrict__ w_var, const float* __restrict__ b_var,
               float* __restrict__ mean_out, float* __restrict__ var_out)
{
    __shared__ unsigned short h1s[64 * 128];
    __shared__ float ptb[112];

    const int t = blockIdx.x;
    const int b = blockIdx.y >> 1;
    const int s0 = (blockIdx.y & 1) * 64;
    const int tid = threadIdx.x;

    if (tid < 112)
        ptb[tid] = (tid < Hn) ? (pt[((long)b * Tn + t) * Hn + tid] + b1[tid]) : 0.0f;
    __syncthreads();

    // stage h1: row r = tid>>2 (64 rows), chunks c = (tid&3)*4 + i
    {
        const int r = tid >> 2;
        const int cb = (tid & 3) * 4;
        const float* psrow = ps + ((long)b * Sn + s0 + r) * Hn;
        #pragma unroll
        for (int i = 0; i < 4; ++i) {
            int c = cb + i;
            int k = c * 8;
            short8 q = {0, 0, 0, 0, 0, 0, 0, 0};
            if (k < Hn) {
                float4 v0 = *(const float4*)&psrow[k];
                float4 v1 = *(const float4*)&psrow[k + 4];
                float vv[8] = {v0.x, v0.y, v0.z, v0.w, v1.x, v1.y, v1.z, v1.w};
                #pragma unroll
                for (int j = 0; j < 8; ++j) {
                    int kj = k + j;
                    float x = softplus_f(ptb[kj] + vv[j]);
                    q[j] = (kj < Hn) ? (short)f2bf(x) : (short)0;
                }
            }
            *(short8*)&h1s[r * 128 + (c ^ (r & 7)) * 8] = q;
        }
    }
    __syncthreads();

    const int wid = tid >> 6, lane = tid & 63;
    const int lm = lane & 15, lq = lane >> 4;

    f32x4 acc[7];
    #pragma unroll
    for (int j = 0; j < 7; ++j) acc[j] = (f32x4){0.f, 0.f, 0.f, 0.f};

    #pragma unroll
    for (int ks = 0; ks < 4; ++ks) {
        int row = wid * 16 + lm;
        int p = (ks * 4 + lq) ^ (lm & 7);
        short8 a = *(const short8*)&h1s[row * 128 + p * 8];
        #pragma unroll
        for (int nt = 0; nt < 7; ++nt) {
            short8 bf = *(const short8*)&w2b[(nt * 16 + lm) * 128 + ks * 32 + lq * 8];
            acc[nt] = __builtin_amdgcn_mfma_f32_16x16x32_bf16(a, bf, acc[nt], 0, 0, 0);
        }
    }

    float sM[4] = {}, sV[4] = {};
    #pragma unroll
    for (int nt = 0; nt < 7; ++nt) {
        int g = nt * 16 + lm;
        if (g < Hn) {
            float bg = b2[g], wm = w_mean[g], wv = w_var[g];
            #pragma unroll
            for (int r = 0; r < 4; ++r) {
                float h2 = softplus_f(acc[nt][r] + bg);
                sM[r] = fmaf(h2, wm, sM[r]);
                sV[r] = fmaf(h2, wv, sV[r]);
            }
        }
    }
    #pragma unroll
    for (int off = 1; off < 16; off <<= 1)
        #pragma unroll
        for (int r = 0; r < 4; ++r) {
            sM[r] += __shfl_xor(sM[r], off);
            sV[r] += __shfl_xor(sV[r], off);
        }

    if (lm == 0) {
        const float bm = b_mean[0], bv = b_var[0];
        const long base = ((long)b * Tn + t) * Sn;
        #pragma unroll
        for (int r = 0; r < 4; ++r) {
            int row = s0 + wid * 16 + lq * 4 + r;
            mean_out[base + row] = softplus_f(sM[r] + bm);
            var_out[base + row]  = softplus_f(sV[r] + bv);
        }
    }
}

// ---------------------------------------------------------------------------
extern "C" void kernel_launch(void* const* d_in, const int* in_sizes, int n_in,
                              void* d_out, int out_size, void* d_ws, size_t ws_size,
                              hipStream_t stream)
{
    (void)in_sizes; (void)n_in; (void)out_size; (void)ws_size;

    const float* input  = (const float*)d_in[0];
    const float* mem    = (const float*)d_in[1];
    const float* W_in   = (const float*)d_in[2];
    const float* W1     = (const float*)d_in[3];
    const float* b1     = (const float*)d_in[4];
    const float* W2     = (const float*)d_in[5];
    const float* b2     = (const float*)d_in[6];
    const float* w_mean = (const float*)d_in[7];
    const float* b_mean = (const float*)d_in[8];
    const float* w_var  = (const float*)d_in[9];
    const float* b_var  = (const float*)d_in[10];
    const float* W_out  = (const float*)d_in[11];

    float* out      = (float*)d_out;
    float* attn_out = out;                                  // (T,B,D)
    float* av_out   = out + (long)Tn * Bn * Dn;             // (T,B,S)
    float* mean_out = av_out + (long)Tn * Bn * Sn;          // (B,T,S)
    float* var_out  = mean_out + (long)Bn * Tn * Sn;        // (B,T,S)

    char* p = (char*)d_ws;
    unsigned short* inh   = (unsigned short*)p; p += 2097152;
    unsigned short* inl   = (unsigned short*)p; p += 2097152;
    unsigned short* memh  = (unsigned short*)p; p += 2097152;
    unsigned short* meml  = (unsigned short*)p; p += 2097152;
    unsigned short* winh  = (unsigned short*)p; p += 524288;
    unsigned short* winl  = (unsigned short*)p; p += 524288;
    unsigned short* w1b   = (unsigned short*)p; p += 204800;
    unsigned short* woutb = (unsigned short*)p; p += 1048576;
    unsigned short* w2b   = (unsigned short*)p; p += 28672;
    unsigned short* memTb = (unsigned short*)p; p += 2097152;
    unsigned short* hth   = (unsigned short*)p; p += 2097152;
    unsigned short* htl   = (unsigned short*)p; p += 2097152;
    float* ptb            = (float*)p;          p += 819200;
    float* psb            = (float*)p;          p += 819200;
    float* algn           = (float*)p;          p += 1048576;
    unsigned short* avb   = (unsigned short*)p; p += 524288;
    unsigned short* concatb = (unsigned short*)p; p += 4194304;

    // 0) conversions + memT
    conv_all<<<dim3(2930), 256, 0, stream>>>(
        input, mem, W_in, W1, W_out, W2,
        inh, inl, memh, meml, winh, winl, w1b, woutb, w2b, concatb);
    transpose_mem<<<dim3(Dn / 64, Sn / 64, Bn), 256, 0, stream>>>(mem, memTb);

    // 1) ht = input @ W_in^T  (split in, split bf16 out)
    mfma_gemm<1, 1><<<dim3(Dn / 64, (Bn * Tn) / 128, 1), 256, 0, stream>>>(
        inh, inl, winh, winl, nullptr, hth, htl,
        Dn, Dn, Dn, Dn, Dn, 0L, 0L, 0L);

    // 2) pt = input @ W1[:, :D]^T  (N=100)
    mfma_gemm<0, 0><<<dim3(2, (Bn * Tn) / 128, 1), 256, 0, stream>>>(
        inh, nullptr, w1b, nullptr, ptb, nullptr, nullptr,
        Hn, Dn, Dn, 2 * Dn, Hn, 0L, 0L, 0L);

    // 3) ps = mem @ W1[:, D:]^T
    mfma_gemm<0, 0><<<dim3(2, (Bn * Sn) / 128, 1), 256, 0, stream>>>(
        memh, nullptr, w1b + Dn, nullptr, psb, nullptr, nullptr,
        Hn, Dn, Dn, 2 * Dn, Hn, 0L, 0L, 0L);

    // 4) align = ht @ mem^T, split, batched over b
    mfma_gemm<1, 0><<<dim3(Sn / 64, Tn / 128, Bn), 256, 0, stream>>>(
        hth, htl, memh, meml, algn, nullptr, nullptr,
        Sn, Dn, Dn, Dn, Sn, (long)Tn * Dn, (long)Sn * Dn, (long)Tn * Sn);

    // 5) softmax -> av (fp32 out slot, (T,B,S)) + avb bf16 (b,t,s)
    softmax_k<<<dim3(Bn * Tn), 128, 0, stream>>>(algn, av_out, avb);

    // 6) c = av @ mem -> concatb[:, :D] bf16, batched over b (B = memT)
    mfma_gemm<0, 3><<<dim3(Dn / 64, Tn / 128, Bn), 256, 0, stream>>>(
        avb, nullptr, memTb, nullptr, nullptr, concatb, nullptr,
        Dn, Sn, Sn, Sn, 2 * Dn, (long)Tn * Sn, (long)Dn * Sn, (long)Tn * 2 * Dn);

    // 7) attn_h = tanh(concat @ W_out^T) -> (T,B,D)
    mfma_gemm<0, 2><<<dim3(Dn / 64, (Bn * Tn) / 128, 1), 256, 0, stream>>>(
        concatb, nullptr, woutb, nullptr, attn_out, nullptr, nullptr,
        Dn, 2 * Dn, 2 * Dn, 2 * Dn, Dn, 0L, 0L, 0L);

    // 8) fused MLP
    mlp_mfma2<<<dim3(Tn, Bn * 2), 256, 0, stream>>>(
        ptb, psb, b1, w2b, b2, w_mean, b_mean, w_var, b_var, mean_out, var_out);
}

// Round 5
// 192.542 us; speedup vs baseline: 3.2564x; 1.2856x over previous
//
#include <hip/hip_runtime.h>
#include <math.h>

#define Bn 16
#define Tn 128
#define Sn 128
#define Dn 512
#define Hn 100
#define TT 8

typedef short short8 __attribute__((ext_vector_type(8)));
typedef float f32x4 __attribute__((ext_vector_type(4)));
typedef unsigned short ushort4v __attribute__((ext_vector_type(4)));

__device__ __forceinline__ float softplus_f(float x) {
    return fmaxf(x, 0.0f) + __logf(1.0f + __expf(-fabsf(x)));
}
__device__ __forceinline__ unsigned short f2bf(float f) {
    unsigned u = __float_as_uint(f);
    unsigned r = u + 0x7FFFu + ((u >> 16) & 1u);
    return (unsigned short)(r >> 16);
}
__device__ __forceinline__ float bf2f(unsigned short h) {
    return __uint_as_float(((unsigned)h) << 16);
}
__device__ __forceinline__ unsigned pk2(float a, float b) {
    return (unsigned)f2bf(a) | ((unsigned)f2bf(b) << 16);
}
struct BfPair { unsigned short h, l; };
__device__ __forceinline__ BfPair split2(float x) {
    BfPair p;
    p.h = f2bf(x);
    p.l = f2bf(x - bf2f(p.h));
    return p;
}

// ---------------------------------------------------------------------------
// Fused conversion (same as R4; buffer wiring changed at launch).
// ---------------------------------------------------------------------------
__global__ __launch_bounds__(256)
void conv_all(const float* __restrict__ input, const float* __restrict__ mem,
              const float* __restrict__ W_in, const float* __restrict__ W1,
              const float* __restrict__ W_out, const float* __restrict__ W2,
              unsigned short* __restrict__ inh, unsigned short* __restrict__ inl,
              unsigned short* __restrict__ memh, unsigned short* __restrict__ meml,
              unsigned short* __restrict__ winh, unsigned short* __restrict__ winl,
              unsigned short* __restrict__ w1b, unsigned short* __restrict__ woutb,
              unsigned short* __restrict__ w2b, unsigned short* __restrict__ concatb)
{
    long gid = (long)blockIdx.x * 1024 + (long)threadIdx.x * 4;
    if (gid < 1048576) {
        float4 v = *(const float4*)&input[gid];
        BfPair a = split2(v.x), b = split2(v.y), c = split2(v.z), d = split2(v.w);
        ushort4v h = {a.h, b.h, c.h, d.h};
        ushort4v l = {a.l, b.l, c.l, d.l};
        *(ushort4v*)&inh[gid] = h;
        *(ushort4v*)&inl[gid] = l;
        long row = gid >> 9; int col = (int)(gid & 511);
        *(ushort4v*)&concatb[row * 1024 + 512 + col] = h;
    } else if (gid < 2097152) {
        long e = gid - 1048576;
        float4 v = *(const float4*)&mem[e];
        BfPair a = split2(v.x), b = split2(v.y), c = split2(v.z), d = split2(v.w);
        ushort4v h = {a.h, b.h, c.h, d.h};
        ushort4v l = {a.l, b.l, c.l, d.l};
        *(ushort4v*)&memh[e] = h;
        *(ushort4v*)&meml[e] = l;
    } else if (gid < 2359296) {
        long e = gid - 2097152;
        float4 v = *(const float4*)&W_in[e];
        BfPair a = split2(v.x), b = split2(v.y), c = split2(v.z), d = split2(v.w);
        ushort4v h = {a.h, b.h, c.h, d.h};
        ushort4v l = {a.l, b.l, c.l, d.l};
        *(ushort4v*)&winh[e] = h;
        *(ushort4v*)&winl[e] = l;
    } else if (gid < 2461696) {
        long e = gid - 2359296;
        float4 v = *(const float4*)&W1[e];
        ushort4v h = {f2bf(v.x), f2bf(v.y), f2bf(v.z), f2bf(v.w)};
        *(ushort4v*)&w1b[e] = h;
    } else if (gid < 2985984) {
        long e = gid - 2461696;
        float4 v = *(const float4*)&W_out[e];
        ushort4v h = {f2bf(v.x), f2bf(v.y), f2bf(v.z), f2bf(v.w)};
        *(ushort4v*)&woutb[e] = h;
    } else {
        long e = gid - 2985984;           // [112][128] padded W2
        int n = (int)(e >> 7), k = (int)(e & 127);
        ushort4v h;
        #pragma unroll
        for (int j = 0; j < 4; ++j) {
            int kj = k + j;
            float val = (n < Hn && kj < Hn) ? W2[n * Hn + kj] : 0.0f;
            h[j] = f2bf(val);
        }
        *(ushort4v*)&w2b[n * 128 + k] = h;
    }
}

// ---------------------------------------------------------------------------
__global__ __launch_bounds__(256)
void transpose_mem(const float* __restrict__ mem, unsigned short* __restrict__ memTb)
{
    __shared__ float tile[64][65];
    const int d0 = blockIdx.x * 64, s0 = blockIdx.y * 64, b = blockIdx.z;
    const int tid = threadIdx.x;
    const int r = tid >> 2, cb = (tid & 3) * 16;

    const float* src = mem + ((long)b * Sn + s0 + r) * Dn + d0 + cb;
    #pragma unroll
    for (int j = 0; j < 4; ++j) {
        float4 v = *(const float4*)&src[j * 4];
        tile[r][cb + j * 4 + 0] = v.x;
        tile[r][cb + j * 4 + 1] = v.y;
        tile[r][cb + j * 4 + 2] = v.z;
        tile[r][cb + j * 4 + 3] = v.w;
    }
    __syncthreads();
    unsigned short* dst = memTb + ((long)b * Dn + d0 + r) * Sn + s0 + cb;
    #pragma unroll
    for (int j = 0; j < 4; ++j) {
        ushort4v q;
        q.x = f2bf(tile[cb + j * 4 + 0][r]);
        q.y = f2bf(tile[cb + j * 4 + 1][r]);
        q.z = f2bf(tile[cb + j * 4 + 2][r]);
        q.w = f2bf(tile[cb + j * 4 + 3][r]);
        *(ushort4v*)&dst[j * 4] = q;
    }
}

// ---------------------------------------------------------------------------
// 64x64-tile bf16 MFMA GEMM (NT), BK=64, 256 thr = 4 waves (2x2), wave 32x32.
// XOR swizzle: chunk p = c ^ (row&7). SPLIT: hi+lo inputs, 3 MFMAs.
// KSPLIT: z = kh*16 + batch; computes K/2 slice, C += kh*sKC.
// BSEL: m-tiles in upper half of grid use Bh + BSEL (merged pt+ps).
// EPI 0: fp32 guarded-n (+batch/khalf)   1: bf16 hi/lo out
//     2: tanh + (t,b,d) fp32             3: bf16 out (+batch)
//     4: fp32 + optional bias, unguarded write to padded ldc
// ---------------------------------------------------------------------------
template<int SPLIT, int EPI, int KSPLIT, int BSEL>
__global__ __launch_bounds__(256)
void mfma_gemm2(const unsigned short* __restrict__ Ah, const unsigned short* __restrict__ Al,
                const unsigned short* __restrict__ Bh, const unsigned short* __restrict__ Bl,
                float* __restrict__ C, unsigned short* __restrict__ Cb,
                unsigned short* __restrict__ Cb2, const float* __restrict__ bias,
                int N, int K, int lda, int ldb, int ldc,
                long sA, long sB, long sC, long sKC)
{
    __shared__ __align__(16) unsigned short As_[(SPLIT ? 2 : 1) * 64 * 64];
    __shared__ __align__(16) unsigned short Bs_[(SPLIT ? 2 : 1) * 64 * 64];
    unsigned short* Asl = As_ + 4096;
    unsigned short* Bsl = Bs_ + 4096;

    const int tid = threadIdx.x;
    const int n0 = blockIdx.x * 64;
    const long m0 = (long)blockIdx.y * 64;
    int bz = blockIdx.z, kh = 0;
    if (KSPLIT) { bz = blockIdx.z & 15; kh = blockIdx.z >> 4; }
    Ah += (long)bz * sA;
    Bh += (long)bz * sB;
    if (SPLIT) { Al += (long)bz * sA; Bl += (long)bz * sB; }
    const bool upperB = blockIdx.y >= (gridDim.y >> 1);
    if (BSEL && upperB) Bh += BSEL;

    const int kbeg = KSPLIT ? kh * (K >> 1) : 0;
    const int kend = KSPLIT ? kbeg + (K >> 1) : K;

    const int wid = tid >> 6, lane = tid & 63;
    const int lm = lane & 15, lq = lane >> 4;
    const int wm = wid & 1, wn = wid >> 1;

    const int sr = tid >> 2;          // staging row 0..63
    const int sc = (tid & 3) * 2;     // staging chunk base
    const bool bok = (n0 + sr) < N;

    f32x4 acc[2][2];
    #pragma unroll
    for (int i = 0; i < 2; ++i)
        #pragma unroll
        for (int j = 0; j < 2; ++j)
            acc[i][j] = (f32x4){0.f, 0.f, 0.f, 0.f};

    for (int k0 = kbeg; k0 < kend; k0 += 64) {
        __syncthreads();
        #pragma unroll
        for (int i = 0; i < 2; ++i) {
            int c = sc + i, p = c ^ (sr & 7);
            *(short8*)&As_[sr * 64 + p * 8] =
                *(const short8*)&Ah[(m0 + sr) * lda + k0 + c * 8];
            if (SPLIT)
                *(short8*)&Asl[sr * 64 + p * 8] =
                    *(const short8*)&Al[(m0 + sr) * lda + k0 + c * 8];
        }
        #pragma unroll
        for (int i = 0; i < 2; ++i) {
            int c = sc + i, p = c ^ (sr & 7);
            short8 v = {0, 0, 0, 0, 0, 0, 0, 0};
            short8 vl = {0, 0, 0, 0, 0, 0, 0, 0};
            if (bok) {
                v = *(const short8*)&Bh[(long)(n0 + sr) * ldb + k0 + c * 8];
                if (SPLIT) vl = *(const short8*)&Bl[(long)(n0 + sr) * ldb + k0 + c * 8];
            }
            *(short8*)&Bs_[sr * 64 + p * 8] = v;
            if (SPLIT) *(short8*)&Bsl[sr * 64 + p * 8] = vl;
        }
        __syncthreads();
        #pragma unroll
        for (int kst = 0; kst < 2; ++kst) {
            short8 a[2], b[2], a2[2], b2r[2];
            const int pp = (kst * 4 + lq) ^ (lm & 7);
            #pragma unroll
            for (int mt = 0; mt < 2; ++mt) {
                int row = wm * 32 + mt * 16 + lm;
                a[mt] = *(const short8*)&As_[row * 64 + pp * 8];
                if (SPLIT) a2[mt] = *(const short8*)&Asl[row * 64 + pp * 8];
            }
            #pragma unroll
            for (int nt = 0; nt < 2; ++nt) {
                int row = wn * 32 + nt * 16 + lm;
                b[nt] = *(const short8*)&Bs_[row * 64 + pp * 8];
                if (SPLIT) b2r[nt] = *(const short8*)&Bsl[row * 64 + pp * 8];
            }
            #pragma unroll
            for (int mt = 0; mt < 2; ++mt)
                #pragma unroll
                for (int nt = 0; nt < 2; ++nt) {
                    if (SPLIT) {
                        acc[mt][nt] = __builtin_amdgcn_mfma_f32_16x16x32_bf16(
                            a2[mt], b[nt], acc[mt][nt], 0, 0, 0);
                        acc[mt][nt] = __builtin_amdgcn_mfma_f32_16x16x32_bf16(
                            a[mt], b2r[nt], acc[mt][nt], 0, 0, 0);
                    }
                    acc[mt][nt] = __builtin_amdgcn_mfma_f32_16x16x32_bf16(
                        a[mt], b[nt], acc[mt][nt], 0, 0, 0);
                }
        }
    }

    #pragma unroll
    for (int mt = 0; mt < 2; ++mt)
        #pragma unroll
        for (int nt = 0; nt < 2; ++nt)
            #pragma unroll
            for (int r = 0; r < 4; ++r) {
                long m = m0 + wm * 32 + mt * 16 + lq * 4 + r;
                int n = n0 + wn * 32 + nt * 16 + lm;
                float v = acc[mt][nt][r];
                if (EPI == 0) {
                    if (n < N)
                        C[(long)bz * sC + (long)kh * sKC + m * ldc + n] = v;
                } else if (EPI == 1) {
                    unsigned short h = f2bf(v);
                    Cb[m * ldc + n] = h;
                    Cb2[m * ldc + n] = f2bf(v - bf2f(h));
                } else if (EPI == 2) {
                    long bb = m >> 7, tt = m & 127;
                    C[tt * (Bn * Dn) + bb * Dn + n] = tanhf(v);
                } else if (EPI == 3) {
                    Cb[(long)bz * sC + m * ldc + n] = f2bf(v);
                } else {
                    float bb = (!upperB && n < Hn) ? bias[n] : 0.f;
                    C[m * ldc + n] = v + bb;
                }
            }
}

// ---------------------------------------------------------------------------
// Softmax over S; sums the two K-split partials; writes av (T,B,S) + bf16 avb.
// ---------------------------------------------------------------------------
__global__ __launch_bounds__(128)
void softmax_k(const float* __restrict__ a0, const float* __restrict__ a1,
               float* __restrict__ av_out, unsigned short* __restrict__ avb)
{
    const int bt = blockIdx.x;
    const int b = bt >> 7, t = bt & 127;
    const int s = threadIdx.x;
    float v = a0[(long)bt * Sn + s] + a1[(long)bt * Sn + s];

    float m = v;
    #pragma unroll
    for (int o = 32; o > 0; o >>= 1) m = fmaxf(m, __shfl_xor(m, o));
    __shared__ float red[2];
    if ((s & 63) == 0) red[s >> 6] = m;
    __syncthreads();
    m = fmaxf(red[0], red[1]);

    float e = __expf(v - m);
    float sum = e;
    #pragma unroll
    for (int o = 32; o > 0; o >>= 1) sum += __shfl_xor(sum, o);
    __shared__ float red2[2];
    if ((s & 63) == 0) red2[s >> 6] = sum;
    __syncthreads();
    float inv = 1.0f / (red2[0] + red2[1]);

    float av = e * inv;
    av_out[(long)t * (Bn * Sn) + b * Sn + s] = av;
    avb[(long)bt * Sn + s] = f2bf(av);
}

// ---------------------------------------------------------------------------
// Fused MLP v3. Block = (t-group of 8, b*2 + s-half). 256 thr = 4 waves.
// ptps: padded [4096][128] fp32 (rows 0..2047 = pt + b1, 2048.. = ps; pads 0).
// ps tile in VGPRs across the t-loop; w2 in XOR-swizzled LDS (reused 8 t).
// ---------------------------------------------------------------------------
__global__ __launch_bounds__(256)
void mlp_mfma3(const float* __restrict__ ptps,
               const unsigned short* __restrict__ w2b,
               const float* __restrict__ b2,
               const float* __restrict__ w_mean, const float* __restrict__ b_mean,
               const float* __restrict__ w_var, const float* __restrict__ b_var,
               float* __restrict__ mean_out, float* __restrict__ var_out)
{
    __shared__ __align__(16) unsigned short h1s[64 * 128];
    __shared__ __align__(16) unsigned short w2s[112 * 128];
    __shared__ float ptl[TT][128];
    __shared__ float b2p[112], wmp[112], wvp[112];

    const int tg = blockIdx.x;
    const int b  = blockIdx.y >> 1;
    const int s0 = (blockIdx.y & 1) * 64;
    const int tid = threadIdx.x;

    // stage w2 (swizzled), pt rows, padded small vectors
    #pragma unroll
    for (int i0 = 0; i0 < 7; ++i0) {
        int i = tid + i0 * 256;
        int r = i >> 4, c = i & 15;
        *(short8*)&w2s[r * 128 + (c ^ (r & 7)) * 8] = *(const short8*)&w2b[i * 8];
    }
    {
        int t = tid >> 5, c4 = (tid & 31) * 4;
        *(float4*)&ptl[t][c4] =
            *(const float4*)&ptps[((long)b * Tn + tg * TT + t) * 128 + c4];
    }
    if (tid < 112) {
        b2p[tid] = (tid < Hn) ? b2[tid] : 0.f;
        wmp[tid] = (tid < Hn) ? w_mean[tid] : 0.f;
        wvp[tid] = (tid < Hn) ? w_var[tid] : 0.f;
    }

    // ps tile -> registers (row r, cols [cb*32, cb*32+32))
    const int r = tid >> 2, cb = tid & 3;
    float psreg[32];
    {
        const float* psrow = ptps + (long)(2048 + b * Sn + s0 + r) * 128 + cb * 32;
        #pragma unroll
        for (int i = 0; i < 8; ++i)
            *(float4*)&psreg[i * 4] = *(const float4*)&psrow[i * 4];
    }
    __syncthreads();

    const int wid = tid >> 6, lane = tid & 63;
    const int lm = lane & 15, lq = lane >> 4;
    const float bm = b_mean[0], bv = b_var[0];

    for (int t = 0; t < TT; ++t) {
        // h1 = softplus(ps + pt)  (pads harmless: w2 K-pad is zero)
        #pragma unroll
        for (int i = 0; i < 4; ++i) {
            float4 pa = *(const float4*)&ptl[t][cb * 32 + i * 8];
            float4 pb = *(const float4*)&ptl[t][cb * 32 + i * 8 + 4];
            float x0 = softplus_f(psreg[i * 8 + 0] + pa.x);
            float x1 = softplus_f(psreg[i * 8 + 1] + pa.y);
            float x2 = softplus_f(psreg[i * 8 + 2] + pa.z);
            float x3 = softplus_f(psreg[i * 8 + 3] + pa.w);
            float x4 = softplus_f(psreg[i * 8 + 4] + pb.x);
            float x5 = softplus_f(psreg[i * 8 + 5] + pb.y);
            float x6 = softplus_f(psreg[i * 8 + 6] + pb.z);
            float x7 = softplus_f(psreg[i * 8 + 7] + pb.w);
            uint4 u;
            u.x = pk2(x0, x1); u.y = pk2(x2, x3);
            u.z = pk2(x4, x5); u.w = pk2(x6, x7);
            *(uint4*)&h1s[r * 128 + ((cb * 4 + i) ^ (r & 7)) * 8] = u;
        }
        __syncthreads();

        // h2 = h1 @ W2^T
        f32x4 acc[7];
        #pragma unroll
        for (int j = 0; j < 7; ++j) acc[j] = (f32x4){0.f, 0.f, 0.f, 0.f};
        #pragma unroll
        for (int ks = 0; ks < 4; ++ks) {
            const int p = (ks * 4 + lq) ^ (lm & 7);
            short8 a = *(const short8*)&h1s[(wid * 16 + lm) * 128 + p * 8];
            #pragma unroll
            for (int nt = 0; nt < 7; ++nt) {
                short8 bf = *(const short8*)&w2s[(nt * 16 + lm) * 128 + p * 8];
                acc[nt] = __builtin_amdgcn_mfma_f32_16x16x32_bf16(a, bf, acc[nt], 0, 0, 0);
            }
        }

        // epilogue
        float sM[4] = {}, sV[4] = {};
        #pragma unroll
        for (int nt = 0; nt < 7; ++nt) {
            int g = nt * 16 + lm;
            float bg = b2p[g], wm_ = wmp[g], wv_ = wvp[g];
            #pragma unroll
            for (int rr = 0; rr < 4; ++rr) {
                float h2 = softplus_f(acc[nt][rr] + bg);
                sM[rr] = fmaf(h2, wm_, sM[rr]);
                sV[rr] = fmaf(h2, wv_, sV[rr]);
            }
        }
        #pragma unroll
        for (int off = 1; off < 16; off <<= 1)
            #pragma unroll
            for (int rr = 0; rr < 4; ++rr) {
                sM[rr] += __shfl_xor(sM[rr], off);
                sV[rr] += __shfl_xor(sV[rr], off);
            }
        if (lm == 0) {
            const long base = ((long)b * Tn + tg * TT + t) * Sn + s0;
            #pragma unroll
            for (int rr = 0; rr < 4; ++rr) {
                int row = wid * 16 + lq * 4 + rr;
                mean_out[base + row] = softplus_f(sM[rr] + bm);
                var_out[base + row]  = softplus_f(sV[rr] + bv);
            }
        }
        __syncthreads();
    }
}

// ---------------------------------------------------------------------------
extern "C" void kernel_launch(void* const* d_in, const int* in_sizes, int n_in,
                              void* d_out, int out_size, void* d_ws, size_t ws_size,
                              hipStream_t stream)
{
    (void)in_sizes; (void)n_in; (void)out_size; (void)ws_size;

    const float* input  = (const float*)d_in[0];
    const float* mem    = (const float*)d_in[1];
    const float* W_in   = (const float*)d_in[2];
    const float* W1     = (const float*)d_in[3];
    const float* b1     = (const float*)d_in[4];
    const float* W2     = (const float*)d_in[5];
    const float* b2     = (const float*)d_in[6];
    const float* w_mean = (const float*)d_in[7];
    const float* b_mean = (const float*)d_in[8];
    const float* w_var  = (const float*)d_in[9];
    const float* b_var  = (const float*)d_in[10];
    const float* W_out  = (const float*)d_in[11];

    float* out      = (float*)d_out;
    float* attn_out = out;
    float* av_out   = out + (long)Tn * Bn * Dn;
    float* mean_out = av_out + (long)Tn * Bn * Sn;
    float* var_out  = mean_out + (long)Bn * Tn * Sn;

    char* p = (char*)d_ws;
    unsigned short* inh   = (unsigned short*)p; p += 2097152;   // [2048][512]
    unsigned short* memh  = (unsigned short*)p; p += 2097152;   // contiguous after inh!
    unsigned short* inl   = (unsigned short*)p; p += 2097152;
    unsigned short* meml  = (unsigned short*)p; p += 2097152;
    unsigned short* winh  = (unsigned short*)p; p += 524288;
    unsigned short* winl  = (unsigned short*)p; p += 524288;
    unsigned short* w1b   = (unsigned short*)p; p += 204800;
    unsigned short* woutb = (unsigned short*)p; p += 1048576;
    unsigned short* w2b   = (unsigned short*)p; p += 28672;
    unsigned short* memTb = (unsigned short*)p; p += 2097152;
    unsigned short* hth   = (unsigned short*)p; p += 2097152;
    unsigned short* htl   = (unsigned short*)p; p += 2097152;
    float* ptps           = (float*)p;          p += 2097152;   // [4096][128]
    float* algn           = (float*)p;          p += 2097152;   // 2 x [16][128][128]
    unsigned short* avb   = (unsigned short*)p; p += 524288;
    unsigned short* concatb = (unsigned short*)p; p += 4194304;

    // 0) conversions + memT
    conv_all<<<dim3(2930), 256, 0, stream>>>(
        input, mem, W_in, W1, W_out, W2,
        inh, inl, memh, meml, winh, winl, w1b, woutb, w2b, concatb);
    transpose_mem<<<dim3(Dn / 64, Sn / 64, Bn), 256, 0, stream>>>(mem, memTb);

    // 1) ht = input @ W_in^T  (split in, hi/lo bf16 out)   grid 256 blocks
    mfma_gemm2<1, 1, 0, 0><<<dim3(8, 32), 256, 0, stream>>>(
        inh, inl, winh, winl, nullptr, hth, htl, nullptr,
        Dn, Dn, Dn, Dn, Dn, 0L, 0L, 0L, 0L);

    // 2) pt+ps merged: [inh;memh] (4096x512) @ W1 halves -> padded ptps [4096][128]
    mfma_gemm2<0, 4, 0, 512><<<dim3(2, 64), 256, 0, stream>>>(
        inh, nullptr, w1b, nullptr, ptps, nullptr, nullptr, b1,
        Hn, Dn, Dn, 2 * Dn, 128, 0L, 0L, 0L, 0L);

    // 3) align = ht @ mem^T, split, K-split x2: z = kh*16 + b   grid 128 blocks
    mfma_gemm2<1, 0, 1, 0><<<dim3(2, 2, 32), 256, 0, stream>>>(
        hth, htl, memh, meml, algn, nullptr, nullptr, nullptr,
        Sn, Dn, Dn, Dn, Sn, (long)Tn * Dn, (long)Sn * Dn,
        (long)Tn * Sn, (long)Bn * Tn * Sn);

    // 4) softmax (sums partials) -> av_out (T,B,S) + avb bf16
    softmax_k<<<dim3(Bn * Tn), 128, 0, stream>>>(
        algn, algn + (long)Bn * Tn * Sn, av_out, avb);

    // 5) c = av @ mem -> concatb[:, :D], batched   grid 256 blocks
    mfma_gemm2<0, 3, 0, 0><<<dim3(8, 2, 16), 256, 0, stream>>>(
        avb, nullptr, memTb, nullptr, nullptr, concatb, nullptr, nullptr,
        Dn, Sn, Sn, Sn, 2 * Dn, (long)Tn * Sn, (long)Dn * Sn,
        (long)Tn * 2 * Dn, 0L);

    // 6) attn_h = tanh(concat @ W_out^T) -> (T,B,D)   grid 256 blocks
    mfma_gemm2<0, 2, 0, 0><<<dim3(8, 32), 256, 0, stream>>>(
        concatb, nullptr, woutb, nullptr, attn_out, nullptr, nullptr, nullptr,
        Dn, 2 * Dn, 2 * Dn, 2 * Dn, Dn, 0L, 0L, 0L, 0L);

    // 7) fused MLP   grid 512 blocks
    mlp_mfma3<<<dim3(Tn / TT, Bn * 2), 256, 0, stream>>>(
        ptps, w2b, b2, w_mean, b_mean, w_var, b_var, mean_out, var_out);
}

// Round 6
// 173.666 us; speedup vs baseline: 3.6103x; 1.1087x over previous
//
#include <hip/hip_runtime.h>
#include <hip/hip_bf16.h>
#include <math.h>

#define Bn 16
#define Tn 128
#define Sn 128
#define Dn 512
#define Hn 100
#define TT 2

typedef short short8 __attribute__((ext_vector_type(8)));
typedef float f32x4 __attribute__((ext_vector_type(4)));
typedef unsigned short ushort4v __attribute__((ext_vector_type(4)));

__device__ __forceinline__ float softplus_f(float x) {
    return fmaxf(x, 0.0f) + __logf(1.0f + __expf(-fabsf(x)));
}
__device__ __forceinline__ unsigned short f2bf(float f) {
    unsigned u = __float_as_uint(f);
    unsigned r = u + 0x7FFFu + ((u >> 16) & 1u);
    return (unsigned short)(r >> 16);
}
__device__ __forceinline__ float bf2f(unsigned short h) {
    return __uint_as_float(((unsigned)h) << 16);
}
__device__ __forceinline__ unsigned pkrn(float a, float b) {
    __hip_bfloat162 h = __float22bfloat162_rn(float2{a, b});
    return *reinterpret_cast<unsigned*>(&h);
}
struct BfPair { unsigned short h, l; };
__device__ __forceinline__ BfPair split2(float x) {
    BfPair p;
    p.h = f2bf(x);
    p.l = f2bf(x - bf2f(p.h));
    return p;
}

// ---------------------------------------------------------------------------
// Fused conversion + mem transpose (blocks >= 2930 do the transpose).
// ---------------------------------------------------------------------------
__global__ __launch_bounds__(256)
void conv_trans(const float* __restrict__ input, const float* __restrict__ mem,
                const float* __restrict__ W_in, const float* __restrict__ W1,
                const float* __restrict__ W_out, const float* __restrict__ W2,
                unsigned short* __restrict__ inh, unsigned short* __restrict__ inl,
                unsigned short* __restrict__ memh, unsigned short* __restrict__ meml,
                unsigned short* __restrict__ winh, unsigned short* __restrict__ winl,
                unsigned short* __restrict__ w1b, unsigned short* __restrict__ woutb,
                unsigned short* __restrict__ w2b, unsigned short* __restrict__ concatb,
                unsigned short* __restrict__ memTb)
{
    __shared__ float tile[64][65];
    const int bx = blockIdx.x;
    if (bx >= 2930) {
        // ---- transpose path ----
        const int b2x = bx - 2930;
        const int d0 = (b2x & 7) * 64, s0 = ((b2x >> 3) & 1) * 64, b = b2x >> 4;
        const int tid = threadIdx.x;
        const int r = tid >> 2, cb = (tid & 3) * 16;
        const float* src = mem + ((long)b * Sn + s0 + r) * Dn + d0 + cb;
        #pragma unroll
        for (int j = 0; j < 4; ++j) {
            float4 v = *(const float4*)&src[j * 4];
            tile[r][cb + j * 4 + 0] = v.x;
            tile[r][cb + j * 4 + 1] = v.y;
            tile[r][cb + j * 4 + 2] = v.z;
            tile[r][cb + j * 4 + 3] = v.w;
        }
        __syncthreads();
        unsigned short* dst = memTb + ((long)b * Dn + d0 + r) * Sn + s0 + cb;
        #pragma unroll
        for (int j = 0; j < 4; ++j) {
            ushort4v q;
            q.x = f2bf(tile[cb + j * 4 + 0][r]);
            q.y = f2bf(tile[cb + j * 4 + 1][r]);
            q.z = f2bf(tile[cb + j * 4 + 2][r]);
            q.w = f2bf(tile[cb + j * 4 + 3][r]);
            *(ushort4v*)&dst[j * 4] = q;
        }
        return;
    }
    long gid = (long)bx * 1024 + (long)threadIdx.x * 4;
    if (gid < 1048576) {
        float4 v = *(const float4*)&input[gid];
        BfPair a = split2(v.x), b = split2(v.y), c = split2(v.z), d = split2(v.w);
        ushort4v h = {a.h, b.h, c.h, d.h};
        ushort4v l = {a.l, b.l, c.l, d.l};
        *(ushort4v*)&inh[gid] = h;
        *(ushort4v*)&inl[gid] = l;
        long row = gid >> 9; int col = (int)(gid & 511);
        *(ushort4v*)&concatb[row * 1024 + 512 + col] = h;
    } else if (gid < 2097152) {
        long e = gid - 1048576;
        float4 v = *(const float4*)&mem[e];
        BfPair a = split2(v.x), b = split2(v.y), c = split2(v.z), d = split2(v.w);
        ushort4v h = {a.h, b.h, c.h, d.h};
        ushort4v l = {a.l, b.l, c.l, d.l};
        *(ushort4v*)&memh[e] = h;
        *(ushort4v*)&meml[e] = l;
    } else if (gid < 2359296) {
        long e = gid - 2097152;
        float4 v = *(const float4*)&W_in[e];
        BfPair a = split2(v.x), b = split2(v.y), c = split2(v.z), d = split2(v.w);
        ushort4v h = {a.h, b.h, c.h, d.h};
        ushort4v l = {a.l, b.l, c.l, d.l};
        *(ushort4v*)&winh[e] = h;
        *(ushort4v*)&winl[e] = l;
    } else if (gid < 2461696) {
        long e = gid - 2359296;
        float4 v = *(const float4*)&W1[e];
        ushort4v h = {f2bf(v.x), f2bf(v.y), f2bf(v.z), f2bf(v.w)};
        *(ushort4v*)&w1b[e] = h;
    } else if (gid < 2985984) {
        long e = gid - 2461696;
        float4 v = *(const float4*)&W_out[e];
        ushort4v h = {f2bf(v.x), f2bf(v.y), f2bf(v.z), f2bf(v.w)};
        *(ushort4v*)&woutb[e] = h;
    } else {
        long e = gid - 2985984;           // [112][128] padded W2
        int n = (int)(e >> 7), k = (int)(e & 127);
        ushort4v h;
        #pragma unroll
        for (int j = 0; j < 4; ++j) {
            int kj = k + j;
            float val = (n < Hn && kj < Hn) ? W2[n * Hn + kj] : 0.0f;
            h[j] = f2bf(val);
        }
        *(ushort4v*)&w2b[n * 128 + k] = h;
    }
}

// ---------------------------------------------------------------------------
// 64x64-tile bf16 MFMA GEMM body (NT). BK=64, 256 thr = 4 waves (2x2).
// XOR swizzle chunk p = c ^ (row&7). SPLIT: hi+lo, 3 MFMAs.
// KSPLIT (0 or 4): bz = z&15, kh = z>>4; C += kh*sKC.
// BSEL: m-tiles with by >= upperThresh use Bh + BSEL.
// EPI 0: fp32 guarded-n  1: bf16 hi/lo  2: tanh +(t,b,d)  3: bf16  4: fp32+bias padded
// ---------------------------------------------------------------------------
template<int SPLIT, int EPI, int KSPLIT, int BSEL>
__device__ __forceinline__
void gemm_body(int bx, int by, int bz_in, int upperThresh,
               const unsigned short* __restrict__ Ah, const unsigned short* __restrict__ Al,
               const unsigned short* __restrict__ Bh, const unsigned short* __restrict__ Bl,
               float* __restrict__ C, unsigned short* __restrict__ Cb,
               unsigned short* __restrict__ Cb2, const float* __restrict__ bias,
               int N, int K, int lda, int ldb, int ldc,
               long sA, long sB, long sC, long sKC,
               unsigned short* As_, unsigned short* Bs_)
{
    unsigned short* Asl = As_ + 4096;
    unsigned short* Bsl = Bs_ + 4096;

    const int tid = threadIdx.x;
    const int n0 = bx * 64;
    const long m0 = (long)by * 64;
    int bz = bz_in, kh = 0;
    if (KSPLIT) { bz = bz_in & 15; kh = bz_in >> 4; }
    Ah += (long)bz * sA;
    Bh += (long)bz * sB;
    if (SPLIT) { Al += (long)bz * sA; Bl += (long)bz * sB; }
    const bool upperB = BSEL && (by >= upperThresh);
    if (upperB) Bh += BSEL;

    const int kbeg = KSPLIT ? kh * (K / KSPLIT) : 0;
    const int kend = KSPLIT ? kbeg + (K / KSPLIT) : K;

    const int wid = tid >> 6, lane = tid & 63;
    const int lm = lane & 15, lq = lane >> 4;
    const int wm = wid & 1, wn = wid >> 1;

    const int sr = tid >> 2;
    const int sc = (tid & 3) * 2;
    const bool bok = (n0 + sr) < N;

    f32x4 acc[2][2];
    #pragma unroll
    for (int i = 0; i < 2; ++i)
        #pragma unroll
        for (int j = 0; j < 2; ++j)
            acc[i][j] = (f32x4){0.f, 0.f, 0.f, 0.f};

    for (int k0 = kbeg; k0 < kend; k0 += 64) {
        __syncthreads();
        #pragma unroll
        for (int i = 0; i < 2; ++i) {
            int c = sc + i, p = c ^ (sr & 7);
            *(short8*)&As_[sr * 64 + p * 8] =
                *(const short8*)&Ah[(m0 + sr) * lda + k0 + c * 8];
            if (SPLIT)
                *(short8*)&Asl[sr * 64 + p * 8] =
                    *(const short8*)&Al[(m0 + sr) * lda + k0 + c * 8];
        }
        #pragma unroll
        for (int i = 0; i < 2; ++i) {
            int c = sc + i, p = c ^ (sr & 7);
            short8 v = {0, 0, 0, 0, 0, 0, 0, 0};
            short8 vl = {0, 0, 0, 0, 0, 0, 0, 0};
            if (bok) {
                v = *(const short8*)&Bh[(long)(n0 + sr) * ldb + k0 + c * 8];
                if (SPLIT) vl = *(const short8*)&Bl[(long)(n0 + sr) * ldb + k0 + c * 8];
            }
            *(short8*)&Bs_[sr * 64 + p * 8] = v;
            if (SPLIT) *(short8*)&Bsl[sr * 64 + p * 8] = vl;
        }
        __syncthreads();
        #pragma unroll
        for (int kst = 0; kst < 2; ++kst) {
            short8 a[2], b[2], a2[2], b2r[2];
            const int pp = (kst * 4 + lq) ^ (lm & 7);
            #pragma unroll
            for (int mt = 0; mt < 2; ++mt) {
                int row = wm * 32 + mt * 16 + lm;
                a[mt] = *(const short8*)&As_[row * 64 + pp * 8];
                if (SPLIT) a2[mt] = *(const short8*)&Asl[row * 64 + pp * 8];
            }
            #pragma unroll
            for (int nt = 0; nt < 2; ++nt) {
                int row = wn * 32 + nt * 16 + lm;
                b[nt] = *(const short8*)&Bs_[row * 64 + pp * 8];
                if (SPLIT) b2r[nt] = *(const short8*)&Bsl[row * 64 + pp * 8];
            }
            #pragma unroll
            for (int mt = 0; mt < 2; ++mt)
                #pragma unroll
                for (int nt = 0; nt < 2; ++nt) {
                    if (SPLIT) {
                        acc[mt][nt] = __builtin_amdgcn_mfma_f32_16x16x32_bf16(
                            a2[mt], b[nt], acc[mt][nt], 0, 0, 0);
                        acc[mt][nt] = __builtin_amdgcn_mfma_f32_16x16x32_bf16(
                            a[mt], b2r[nt], acc[mt][nt], 0, 0, 0);
                    }
                    acc[mt][nt] = __builtin_amdgcn_mfma_f32_16x16x32_bf16(
                        a[mt], b[nt], acc[mt][nt], 0, 0, 0);
                }
        }
    }

    #pragma unroll
    for (int mt = 0; mt < 2; ++mt)
        #pragma unroll
        for (int nt = 0; nt < 2; ++nt)
            #pragma unroll
            for (int r = 0; r < 4; ++r) {
                long m = m0 + wm * 32 + mt * 16 + lq * 4 + r;
                int n = n0 + wn * 32 + nt * 16 + lm;
                float v = acc[mt][nt][r];
                if (EPI == 0) {
                    if (n < N)
                        C[(long)bz * sC + (long)kh * sKC + m * ldc + n] = v;
                } else if (EPI == 1) {
                    unsigned short h = f2bf(v);
                    Cb[m * ldc + n] = h;
                    Cb2[m * ldc + n] = f2bf(v - bf2f(h));
                } else if (EPI == 2) {
                    long bb = m >> 7, tt = m & 127;
                    C[tt * (Bn * Dn) + bb * Dn + n] = tanhf(v);
                } else if (EPI == 3) {
                    Cb[(long)bz * sC + m * ldc + n] = f2bf(v);
                } else {
                    float bb = (!upperB && n < Hn) ? bias[n] : 0.f;
                    C[m * ldc + n] = v + bb;
                }
            }
}

template<int SPLIT, int EPI, int KSPLIT, int BSEL>
__global__ __launch_bounds__(256)
void mfma_gemm3(const unsigned short* __restrict__ Ah, const unsigned short* __restrict__ Al,
                const unsigned short* __restrict__ Bh, const unsigned short* __restrict__ Bl,
                float* __restrict__ C, unsigned short* __restrict__ Cb,
                unsigned short* __restrict__ Cb2, const float* __restrict__ bias,
                int N, int K, int lda, int ldb, int ldc,
                long sA, long sB, long sC, long sKC)
{
    __shared__ __align__(16) unsigned short As_[(SPLIT ? 2 : 1) * 4096];
    __shared__ __align__(16) unsigned short Bs_[(SPLIT ? 2 : 1) * 4096];
    gemm_body<SPLIT, EPI, KSPLIT, BSEL>(blockIdx.x, blockIdx.y, blockIdx.z,
        (int)(gridDim.y >> 1), Ah, Al, Bh, Bl, C, Cb, Cb2, bias,
        N, K, lda, ldb, ldc, sA, sB, sC, sKC, As_, Bs_);
}

// ---------------------------------------------------------------------------
// Merged independent GEMMs: blocks 0..255 = ht (split), 256..383 = pt+ps.
// ---------------------------------------------------------------------------
__global__ __launch_bounds__(256)
void gemm_ht_ptps(const unsigned short* __restrict__ inh, const unsigned short* __restrict__ inl,
                  const unsigned short* __restrict__ winh, const unsigned short* __restrict__ winl,
                  unsigned short* __restrict__ hth, unsigned short* __restrict__ htl,
                  const unsigned short* __restrict__ w1b, float* __restrict__ ptps,
                  const float* __restrict__ b1)
{
    __shared__ __align__(16) unsigned short As_[8192];
    __shared__ __align__(16) unsigned short Bs_[8192];
    const int id = blockIdx.x;
    if (id < 256) {
        gemm_body<1, 1, 0, 0>(id & 7, id >> 3, 0, 0,
            inh, inl, winh, winl, nullptr, hth, htl, nullptr,
            Dn, Dn, Dn, Dn, Dn, 0L, 0L, 0L, 0L, As_, Bs_);
    } else {
        const int j = id - 256;
        gemm_body<0, 4, 0, 512>(j & 1, j >> 1, 0, 32,
            inh, nullptr, w1b, nullptr, ptps, nullptr, nullptr, b1,
            Hn, Dn, Dn, 2 * Dn, 128, 0L, 0L, 0L, 0L, As_, Bs_);
    }
}

// ---------------------------------------------------------------------------
// Softmax over S; sums 4 K-split partials; writes av (T,B,S) + bf16 avb.
// ---------------------------------------------------------------------------
__global__ __launch_bounds__(128)
void softmax_k4(const float* __restrict__ algn, long kstride,
                float* __restrict__ av_out, unsigned short* __restrict__ avb)
{
    const int bt = blockIdx.x;
    const int b = bt >> 7, t = bt & 127;
    const int s = threadIdx.x;
    const long o = (long)bt * Sn + s;
    float v = algn[o] + algn[o + kstride] + algn[o + 2 * kstride] + algn[o + 3 * kstride];

    float m = v;
    #pragma unroll
    for (int off = 32; off > 0; off >>= 1) m = fmaxf(m, __shfl_xor(m, off));
    __shared__ float red[2];
    if ((s & 63) == 0) red[s >> 6] = m;
    __syncthreads();
    m = fmaxf(red[0], red[1]);

    float e = __expf(v - m);
    float sum = e;
    #pragma unroll
    for (int off = 32; off > 0; off >>= 1) sum += __shfl_xor(sum, off);
    __shared__ float red2[2];
    if ((s & 63) == 0) red2[s >> 6] = sum;
    __syncthreads();
    float inv = 1.0f / (red2[0] + red2[1]);

    float av = e * inv;
    av_out[(long)t * (Bn * Sn) + b * Sn + s] = av;
    avb[o] = f2bf(av);
}

// ---------------------------------------------------------------------------
// Fused MLP v4. Block = (t-group of TT=2, b*2 + s-half). 256 thr = 4 waves.
// ptps padded [4096][128] fp32. ps tile in VGPRs (strided chunks cb+4i);
// pt rows in LDS with bank-offset swizzle col+4*(col>>5); w2 in swizzled LDS.
// Packed bf16 convert via v_cvt_pk_bf16_f32.
// ---------------------------------------------------------------------------
__global__ __launch_bounds__(256)
void mlp_mfma4(const float* __restrict__ ptps,
               const unsigned short* __restrict__ w2b,
               const float* __restrict__ b2,
               const float* __restrict__ w_mean, const float* __restrict__ b_mean,
               const float* __restrict__ w_var, const float* __restrict__ b_var,
               float* __restrict__ mean_out, float* __restrict__ var_out)
{
    __shared__ __align__(16) unsigned short h1s[64 * 128];
    __shared__ __align__(16) unsigned short w2s[112 * 128];
    __shared__ float ptl[TT][140];
    __shared__ float b2p[112], wmp[112], wvp[112];

    const int tg = blockIdx.x;
    const int b  = blockIdx.y >> 1;
    const int s0 = (blockIdx.y & 1) * 64;
    const int tid = threadIdx.x;

    // stage w2 (swizzled)
    #pragma unroll
    for (int i0 = 0; i0 < 7; ++i0) {
        int i = tid + i0 * 256;
        int r_ = i >> 4, c_ = i & 15;
        *(short8*)&w2s[r_ * 128 + (c_ ^ (r_ & 7)) * 8] = *(const short8*)&w2b[i * 8];
    }
    // stage pt rows (1 float/thread, bank-offset layout)
    {
        int t = tid >> 7, c = tid & 127;
        ptl[t][c + 4 * (c >> 5)] =
            ptps[((long)b * Tn + tg * TT + t) * 128 + c];
    }
    if (tid < 112) {
        b2p[tid] = (tid < Hn) ? b2[tid] : 0.f;
        wmp[tid] = (tid < Hn) ? w_mean[tid] : 0.f;
        wvp[tid] = (tid < Hn) ? w_var[tid] : 0.f;
    }

    // ps tile -> registers: row r, strided chunks c = cb + 4*i (8 cols each)
    const int r = tid >> 2, cb = tid & 3;
    float psreg[4][8];
    {
        const float* psrow = ptps + (long)(2048 + b * Sn + s0 + r) * 128;
        #pragma unroll
        for (int i = 0; i < 4; ++i) {
            int col = (cb + 4 * i) * 8;
            *(float4*)&psreg[i][0] = *(const float4*)&psrow[col];
            *(float4*)&psreg[i][4] = *(const float4*)&psrow[col + 4];
        }
    }
    __syncthreads();

    const int wid = tid >> 6, lane = tid & 63;
    const int lm = lane & 15, lq = lane >> 4;
    const float bm = b_mean[0], bv = b_var[0];

    for (int t = 0; t < TT; ++t) {
        // h1 = softplus(ps + pt), packed to bf16, swizzled LDS store
        #pragma unroll
        for (int i = 0; i < 4; ++i) {
            const int c = cb + 4 * i;
            const int col = c * 8;
            const int base = col + 4 * (col >> 5);   // = cb*8 + 36*i
            float4 pa = *(const float4*)&ptl[t][base];
            float4 pb = *(const float4*)&ptl[t][base + 4];
            float x0 = softplus_f(psreg[i][0] + pa.x);
            float x1 = softplus_f(psreg[i][1] + pa.y);
            float x2 = softplus_f(psreg[i][2] + pa.z);
            float x3 = softplus_f(psreg[i][3] + pa.w);
            float x4 = softplus_f(psreg[i][4] + pb.x);
            float x5 = softplus_f(psreg[i][5] + pb.y);
            float x6 = softplus_f(psreg[i][6] + pb.z);
            float x7 = softplus_f(psreg[i][7] + pb.w);
            uint4 u;
            u.x = pkrn(x0, x1); u.y = pkrn(x2, x3);
            u.z = pkrn(x4, x5); u.w = pkrn(x6, x7);
            *(uint4*)&h1s[r * 128 + (c ^ (r & 7)) * 8] = u;
        }
        __syncthreads();

        // h2 = h1 @ W2^T
        f32x4 acc[7];
        #pragma unroll
        for (int j = 0; j < 7; ++j) acc[j] = (f32x4){0.f, 0.f, 0.f, 0.f};
        #pragma unroll
        for (int ks = 0; ks < 4; ++ks) {
            const int p = (ks * 4 + lq) ^ (lm & 7);
            short8 a = *(const short8*)&h1s[(wid * 16 + lm) * 128 + p * 8];
            #pragma unroll
            for (int nt = 0; nt < 7; ++nt) {
                short8 bf = *(const short8*)&w2s[(nt * 16 + lm) * 128 + p * 8];
                acc[nt] = __builtin_amdgcn_mfma_f32_16x16x32_bf16(a, bf, acc[nt], 0, 0, 0);
            }
        }

        // epilogue
        float sM[4] = {}, sV[4] = {};
        #pragma unroll
        for (int nt = 0; nt < 7; ++nt) {
            int g = nt * 16 + lm;
            float bg = b2p[g], wm_ = wmp[g], wv_ = wvp[g];
            #pragma unroll
            for (int rr = 0; rr < 4; ++rr) {
                float h2 = softplus_f(acc[nt][rr] + bg);
                sM[rr] = fmaf(h2, wm_, sM[rr]);
                sV[rr] = fmaf(h2, wv_, sV[rr]);
            }
        }
        #pragma unroll
        for (int off = 1; off < 16; off <<= 1)
            #pragma unroll
            for (int rr = 0; rr < 4; ++rr) {
                sM[rr] += __shfl_xor(sM[rr], off);
                sV[rr] += __shfl_xor(sV[rr], off);
            }
        if (lm == 0) {
            const long base = ((long)b * Tn + tg * TT + t) * Sn + s0;
            #pragma unroll
            for (int rr = 0; rr < 4; ++rr) {
                int row = wid * 16 + lq * 4 + rr;
                mean_out[base + row] = softplus_f(sM[rr] + bm);
                var_out[base + row]  = softplus_f(sV[rr] + bv);
            }
        }
        __syncthreads();
    }
}

// ---------------------------------------------------------------------------
extern "C" void kernel_launch(void* const* d_in, const int* in_sizes, int n_in,
                              void* d_out, int out_size, void* d_ws, size_t ws_size,
                              hipStream_t stream)
{
    (void)in_sizes; (void)n_in; (void)out_size; (void)ws_size;

    const float* input  = (const float*)d_in[0];
    const float* mem    = (const float*)d_in[1];
    const float* W_in   = (const float*)d_in[2];
    const float* W1     = (const float*)d_in[3];
    const float* b1     = (const float*)d_in[4];
    const float* W2     = (const float*)d_in[5];
    const float* b2     = (const float*)d_in[6];
    const float* w_mean = (const float*)d_in[7];
    const float* b_mean = (const float*)d_in[8];
    const float* w_var  = (const float*)d_in[9];
    const float* b_var  = (const float*)d_in[10];
    const float* W_out  = (const float*)d_in[11];

    float* out      = (float*)d_out;
    float* attn_out = out;
    float* av_out   = out + (long)Tn * Bn * Dn;
    float* mean_out = av_out + (long)Tn * Bn * Sn;
    float* var_out  = mean_out + (long)Bn * Tn * Sn;

    char* p = (char*)d_ws;
    unsigned short* inh   = (unsigned short*)p; p += 2097152;   // [2048][512]
    unsigned short* memh  = (unsigned short*)p; p += 2097152;   // contiguous after inh!
    unsigned short* inl   = (unsigned short*)p; p += 2097152;
    unsigned short* meml  = (unsigned short*)p; p += 2097152;
    unsigned short* winh  = (unsigned short*)p; p += 524288;
    unsigned short* winl  = (unsigned short*)p; p += 524288;
    unsigned short* w1b   = (unsigned short*)p; p += 204800;
    unsigned short* woutb = (unsigned short*)p; p += 1048576;
    unsigned short* w2b   = (unsigned short*)p; p += 28672;
    unsigned short* memTb = (unsigned short*)p; p += 2097152;
    unsigned short* hth   = (unsigned short*)p; p += 2097152;
    unsigned short* htl   = (unsigned short*)p; p += 2097152;
    float* ptps           = (float*)p;          p += 2097152;   // [4096][128]
    float* algn           = (float*)p;          p += 4194304;   // 4 x [16][128][128]
    unsigned short* avb   = (unsigned short*)p; p += 524288;
    unsigned short* concatb = (unsigned short*)p; p += 4194304;

    const long kstride = (long)Bn * Tn * Sn;

    // 0) conversions + mem transpose (merged)
    conv_trans<<<dim3(2930 + 256), 256, 0, stream>>>(
        input, mem, W_in, W1, W_out, W2,
        inh, inl, memh, meml, winh, winl, w1b, woutb, w2b, concatb, memTb);

    // 1) ht (split, hi/lo out) + pt/ps (padded ptps) merged   384 blocks
    gemm_ht_ptps<<<dim3(384), 256, 0, stream>>>(
        inh, inl, winh, winl, hth, htl, w1b, ptps, b1);

    // 2) align = ht @ mem^T, split, K-split x4   grid 256 blocks
    mfma_gemm3<1, 0, 4, 0><<<dim3(2, 2, 64), 256, 0, stream>>>(
        hth, htl, memh, meml, algn, nullptr, nullptr, nullptr,
        Sn, Dn, Dn, Dn, Sn, (long)Tn * Dn, (long)Sn * Dn,
        (long)Tn * Sn, kstride);

    // 3) softmax (sums 4 partials) -> av_out (T,B,S) + avb bf16
    softmax_k4<<<dim3(Bn * Tn), 128, 0, stream>>>(algn, kstride, av_out, avb);

    // 4) c = av @ mem -> concatb[:, :D], batched   256 blocks
    mfma_gemm3<0, 3, 0, 0><<<dim3(8, 2, 16), 256, 0, stream>>>(
        avb, nullptr, memTb, nullptr, nullptr, concatb, nullptr, nullptr,
        Dn, Sn, Sn, Sn, 2 * Dn, (long)Tn * Sn, (long)Dn * Sn,
        (long)Tn * 2 * Dn, 0L);

    // 5) attn_h = tanh(concat @ W_out^T) -> (T,B,D)   256 blocks
    mfma_gemm3<0, 2, 0, 0><<<dim3(8, 32), 256, 0, stream>>>(
        concatb, nullptr, woutb, nullptr, attn_out, nullptr, nullptr, nullptr,
        Dn, 2 * Dn, 2 * Dn, 2 * Dn, Dn, 0L, 0L, 0L, 0L);

    // 6) fused MLP   grid 2048 blocks
    mlp_mfma4<<<dim3(Tn / TT, Bn * 2), 256, 0, stream>>>(
        ptps, w2b, b2, w_mean, b_mean, w_var, b_var, mean_out, var_out);
}